// Round 9
// baseline (4963.728 us; speedup 1.0000x reference)
//
#include <hip/hip_runtime.h>
#include <math.h>

#define SEQ 512
#define BATCH 8
#define HID 768
#define G4 3072           // 4*HID
#define CHUNK 128
#define NEGV (-1000000000.0f)

typedef float v4f __attribute__((ext_vector_type(4)));
typedef float v2f __attribute__((ext_vector_type(2)));

__device__ __forceinline__ float sigm(float x) { return 1.0f / (1.0f + expf(-x)); }

// packed fp32 fma (v_pk_fma_f32 on CDNA); fma semantics match the compiler's
// default contraction of a*b+c, so numerics are identical to the scalar code.
__device__ __forceinline__ v2f fma2(v2f a, v2f b, v2f c) {
#if __has_builtin(__builtin_elementwise_fma)
  return __builtin_elementwise_fma(a, b, c);
#else
  v2f r; r.x = __builtin_fmaf(a.x, b.x, c.x); r.y = __builtin_fmaf(a.y, b.y, c.y);
  return r;
#endif
}

__device__ __forceinline__ float wred(float x) {
#pragma unroll
  for (int off = 32; off > 0; off >>= 1) x += __shfl_xor(x, off, 64);
  return x;
}

// ---- device-coherent (bypass L1+L2) memory ops: always correct cross-XCD ----
__device__ __forceinline__ v4f load_f4_sc(const float* p) {
  v4f a;
  asm volatile("global_load_dwordx4 %0, %1, off sc0 sc1\n\ts_waitcnt vmcnt(0)"
               : "=v"(a) : "v"(p) : "memory");
  return a;
}
__device__ __forceinline__ int load_i_sc(const int* p) {
  int r;
  asm volatile("global_load_dword %0, %1, off sc0 sc1\n\ts_waitcnt vmcnt(0)"
               : "=v"(r) : "v"(p) : "memory");
  return r;
}
__device__ __forceinline__ void store_f_sc(float* p, float v) {
  asm volatile("global_store_dword %0, %1, off sc0 sc1" :: "v"(p), "v"(v) : "memory");
}
__device__ __forceinline__ void store_i_sc(int* p, int v) {
  asm volatile("global_store_dword %0, %1, off sc0 sc1" :: "v"(p), "v"(v) : "memory");
}

// ---- VALU-pipe 32-lane reduction: 4x row_ror (row sums) + row_bcast15 ----
template <int CTRL, int RMASK>
__device__ __forceinline__ float dpp_add(float x) {
  int y = __builtin_amdgcn_update_dpp(0, __float_as_int(x), CTRL, RMASK, 0xF, false);
  return x + __int_as_float(y);
}
__device__ __forceinline__ float reduce32(float x) {
  x = dpp_add<0x121, 0xF>(x);  // row_ror:1
  x = dpp_add<0x122, 0xF>(x);  // row_ror:2
  x = dpp_add<0x124, 0xF>(x);  // row_ror:4
  x = dpp_add<0x128, 0xF>(x);  // row_ror:8  -> every lane holds its 16-row sum
  x = dpp_add<0x142, 0xA>(x);  // row_bcast15 into rows 1,3 -> kq>=16 = 32-sum
  return x;
}

// ---------------------------------------------------------------- init zeros
// flags are PADDED: one 64B line per flag -> flags[(grp*32+jb)*16]
__global__ void k_init(float* __restrict__ hbuf, int* __restrict__ flags) {
  int i = blockIdx.x * blockDim.x + threadIdx.x;
  if (i < 2 * 2 * BATCH * HID) hbuf[i] = 0.0f;   // [par][dir][b][HID]
  if (i < 4096) flags[i] = 0;                    // 128 flags x 16-int pad (+spare)
}

// ------------------------------------------- L1 input projection, one chunk
// ROUND-9: + intra-row LDS padding. Old As[k][tm*8] reads: 16 distinct 16B
// addrs at banks {0,8,16,24}x4 -> 4-way conflict (1.58x, m136). Remap
// col c -> c + ((c>>5)<<2) (skip 4 floats every 32): read start-banks become
// 9*tm-spaced, all distinct, <=2-way overlap (free). Writes stay <=2-way.
// Pure layout change -> bitwise-identical numerics. Keeps round-8 single-tile
// register prefetch (straight-line; round-7 lambda dbuf spilled to scratch).
#define CMAP(c) ((c) + (((c) >> 5) << 2))
__global__ __launch_bounds__(256) void k_proj1(
    const float* __restrict__ emb,
    const float* __restrict__ w_f, const float* __restrict__ b_f,
    const float* __restrict__ w_r, const float* __restrict__ b_r,
    float* __restrict__ xs_f, float* __restrict__ xs_r, int chunk) {
  __shared__ float As[16][144];
  __shared__ float Bs[16][144];
  const int tid = threadIdx.x;
  const int bn0 = blockIdx.x * 128;
  const int bb  = blockIdx.y;
  const int dir = blockIdx.z;
  const float* W    = dir ? w_r : w_f;
  const float* bias = dir ? b_r : b_f;
  float* xs = dir ? xs_r : xs_f;

  v2f acc2[8][4];
#pragma unroll
  for (int i = 0; i < 8; i++)
#pragma unroll
    for (int j = 0; j < 4; j++) acc2[i][j] = (v2f){0.0f, 0.0f};

  const int mload = tid & 127;
  const int kq0   = tid >> 7;
  const int tglob = dir ? (SEQ - 1 - (chunk * CHUNK + mload)) : (chunk * CHUNK + mload);
  const float* arow = emb + (size_t)(bb * SEQ + tglob) * HID;
  const float* brow = W + (size_t)(bn0 + mload) * HID;
  const int tm = tid & 15, tn = tid >> 4;
  const int cw = CMAP(mload);            // swizzled write column
  const int cA = CMAP(tm * 8);           // swizzled read col base (A)
  const int cB = CMAP(tn * 8);           // swizzled read col base (B)

  // per-thread load cursors: rep0 at +0, rep1 at +8 floats (kq = kq0, kq0+2)
  const float* aptr = arow + kq0 * 4;
  const float* bptr = brow + kq0 * 4;
  const int rA = kq0 * 4;          // LDS row base, rep0
  const int rB = (kq0 + 2) * 4;    // LDS row base, rep1

  // prologue: tile 0 -> regs
  float4 a0 = *(const float4*)(aptr);
  float4 a1 = *(const float4*)(aptr + 8);
  float4 b0 = *(const float4*)(bptr);
  float4 b1 = *(const float4*)(bptr + 8);

  for (int kt = 0; kt < HID; kt += 16) {
    // stage current tile regs -> LDS
    As[rA + 0][cw] = a0.x; As[rA + 1][cw] = a0.y;
    As[rA + 2][cw] = a0.z; As[rA + 3][cw] = a0.w;
    As[rB + 0][cw] = a1.x; As[rB + 1][cw] = a1.y;
    As[rB + 2][cw] = a1.z; As[rB + 3][cw] = a1.w;
    Bs[rA + 0][cw] = b0.x; Bs[rA + 1][cw] = b0.y;
    Bs[rA + 2][cw] = b0.z; Bs[rA + 3][cw] = b0.w;
    Bs[rB + 0][cw] = b1.x; Bs[rB + 1][cw] = b1.y;
    Bs[rB + 2][cw] = b1.z; Bs[rB + 3][cw] = b1.w;
    __syncthreads();
    // prefetch next tile (latency spans the compute below)
    if (kt + 16 < HID) {
      a0 = *(const float4*)(aptr + kt + 16);
      a1 = *(const float4*)(aptr + kt + 24);
      b0 = *(const float4*)(bptr + kt + 16);
      b1 = *(const float4*)(bptr + kt + 24);
    }
#pragma unroll
    for (int k = 0; k < 16; k++) {
      float4 c0 = *(const float4*)&As[k][cA];
      float4 c1 = *(const float4*)&As[k][cA + 4];
      float4 d0 = *(const float4*)&Bs[k][cB];
      float4 d1 = *(const float4*)&Bs[k][cB + 4];
      float av[8] = {c0.x, c0.y, c0.z, c0.w, c1.x, c1.y, c1.z, c1.w};
      v2f bv2[4] = {{d0.x, d0.y}, {d0.z, d0.w}, {d1.x, d1.y}, {d1.z, d1.w}};
#pragma unroll
      for (int i = 0; i < 8; i++) {
        v2f avv = {av[i], av[i]};
#pragma unroll
        for (int jj = 0; jj < 4; jj++) acc2[i][jj] = fma2(avv, bv2[jj], acc2[i][jj]);
      }
    }
    __syncthreads();
  }
#pragma unroll
  for (int i = 0; i < 8; i++) {
    int row = tm * 8 + i;
    size_t base = (size_t)(bb * CHUNK + row) * G4 + bn0 + tn * 8;
#pragma unroll
    for (int jj = 0; jj < 4; jj++) {
      xs[base + 2 * jj]     = acc2[i][jj].x + bias[bn0 + tn * 8 + 2 * jj];
      xs[base + 2 * jj + 1] = acc2[i][jj].y + bias[bn0 + tn * 8 + 2 * jj + 1];
    }
  }
}

// ---------------------------------------- L1 recurrence: persistent kernel
// ROUND-9 CHANGE: 128 blocks x 768 threads (was 256 x 384). Mechanism
// (round-6 lesson: coherent-fabric traffic is first-order): per poll sweep,
// flag traffic drops 4x (128 blocks x 32 lines vs 256 x 64), h-stage reads
// drop 2x (128 x 12KB), and each step waits on 32 publishers not 64.
// Per-thread work, LDS layout, and sync protocol logic are unchanged.
// Block = (dir, b-half, 24 j's). Thread (g,kq): j = jb*24+g, kq k-slice.
// ROUND-4: scalar dot chains (chain depth rules). ROUND-8: harr deferred.
__global__ __launch_bounds__(768, 1) void k_rec1(
    const float* __restrict__ whh_f, const float* __restrict__ whh_r,
    const float* __restrict__ xs_f, const float* __restrict__ xs_r,
    float* __restrict__ hbuf, float* __restrict__ cbuf, int* __restrict__ flags,
    float* __restrict__ hf, float* __restrict__ hr, int t0, int init) {
  __shared__ float hlds[4 * HID];
  const int tid = threadIdx.x;
  const int bid = blockIdx.x;          // 0..127
  const int dir = bid >> 6;
  const int bh  = (bid >> 5) & 1;
  const int jb  = bid & 31;
  const int J0  = jb * 24;
  const int grp = dir * 2 + bh;
  const int g  = tid >> 5;             // 0..23
  const int kq = tid & 31;
  const int j  = J0 + g;

  const float* W  = dir ? whh_r : whh_f;
  const float* xs = dir ? xs_r  : xs_f;
  float* harr = dir ? hr : hf;

  // W_hh slice -> registers (once per chunk launch), interleaved k layout
  float wreg[4][24];
#pragma unroll
  for (int gate = 0; gate < 4; gate++) {
#pragma unroll
    for (int q = 0; q < 6; q++) {
      *(v4f*)&wreg[gate][q * 4] =
          *(const v4f*)&W[(size_t)(gate * HID + j) * HID + q * 128 + kq * 4];
    }
  }

  float cc[4];
#pragma unroll
  for (int b = 0; b < 4; b++) cc[b] = 0.0f;
  if (!init && kq == 16) {
#pragma unroll
    for (int b = 0; b < 4; b++) cc[b] = cbuf[bid * 96 + g * 4 + b];
  }

  for (int stp = 0; stp < CHUNK; stp++) {
    const int s = t0 + stp;
    const int par = s & 1;

    // prefetch xs gate values for writers BEFORE the wait (cached loads;
    // cannot sink past the asm memory clobbers in the poll loop)
    float xsv[4][4];
    if (kq == 16) {
#pragma unroll
      for (int b = 0; b < 4; b++) {
        const size_t xbase = (size_t)((bh * 4 + b) * CHUNK + stp) * G4 + j;
#pragma unroll
        for (int gate = 0; gate < 4; gate++)
          xsv[b][gate] = xs[xbase + gate * HID];
      }
    }

    // wait until all 32 blocks of this group published h_{s-1}
    if (tid < 32) {
      const int* fp = flags + (grp * 32 + tid) * 16;   // one line per flag
      while (load_i_sc(fp) < s) { __builtin_amdgcn_s_sleep(4); }
    }
    __syncthreads();

    // stage h_{s-1} (my dir, my 4 b's) into LDS: one 16B per thread
    {
      const float* src = hbuf + (size_t)((par * 2 + dir) * BATCH + bh * 4) * HID + tid * 4;
      *(v4f*)&hlds[tid * 4] = load_f4_sc(src);
    }
    __syncthreads();

    // dots: 4 gates x 4 b over this thread's interleaved k-slice
    float acc[4][4];
#pragma unroll
    for (int gate = 0; gate < 4; gate++)
#pragma unroll
      for (int b = 0; b < 4; b++) acc[gate][b] = 0.0f;
#pragma unroll
    for (int b = 0; b < 4; b++) {
      float hk[24];
#pragma unroll
      for (int q = 0; q < 6; q++)
        *(v4f*)&hk[q * 4] = *(const v4f*)&hlds[b * HID + q * 128 + kq * 4];
#pragma unroll
      for (int gate = 0; gate < 4; gate++)
#pragma unroll
        for (int k = 0; k < 24; k++) acc[gate][b] += wreg[gate][k] * hk[k];
    }
#pragma unroll
    for (int gate = 0; gate < 4; gate++)
#pragma unroll
      for (int b = 0; b < 4; b++) acc[gate][b] = reduce32(acc[gate][b]);

    // writers: LSTM pointwise + publish h (sc stores only on publish path)
    float hv[4];
    int t = 0;
    if (kq == 16) {
      t = dir ? (SEQ - 1 - s) : s;
#pragma unroll
      for (int b = 0; b < 4; b++) {
        const int bg = bh * 4 + b;
        float iv = acc[0][b] + xsv[b][0];
        float fv = acc[1][b] + xsv[b][1];
        float gv = acc[2][b] + xsv[b][2];
        float ov = acc[3][b] + xsv[b][3];
        cc[b] = sigm(fv) * cc[b] + sigm(iv) * tanhf(gv);
        hv[b] = sigm(ov) * tanhf(cc[b]);
        store_f_sc(hbuf + (size_t)(((par ^ 1) * 2 + dir) * BATCH + bg) * HID + j, hv[b]);
      }
    }
    asm volatile("s_waitcnt vmcnt(0)" ::: "memory");
    __syncthreads();
    if (tid == 0) store_i_sc(flags + (grp * 32 + jb) * 16, s + 1);
    // deferred history stores: off the publication critical path
    if (kq == 16) {
#pragma unroll
      for (int b = 0; b < 4; b++)
        harr[(size_t)((bh * 4 + b) * SEQ + t) * HID + j] = hv[b];
    }
  }
  if (kq == 16) {
#pragma unroll
    for (int b = 0; b < 4; b++) cbuf[bid * 96 + g * 4 + b] = cc[b];
  }
}

// ----------------------------------------------------------- hs = hf + hr
__global__ void k_sum(float* __restrict__ hf, const float* __restrict__ hr) {
  int i = blockIdx.x * 256 + threadIdx.x;
  float4 a = ((const float4*)hf)[i];
  float4 b = ((const float4*)hr)[i];
  a.x += b.x; a.y += b.y; a.z += b.z; a.w += b.w;
  ((float4*)hf)[i] = a;
}

// --------------------------------------------------------- windowed attention
__global__ __launch_bounds__(64) void k_attn(
    const float* __restrict__ hs, const float* __restrict__ attn_w,
    const float* __restrict__ attn_b, float* __restrict__ att) {
  const int l = threadIdx.x;
  const int s = blockIdx.x, b = blockIdx.y;
  const float* hrow = hs + (size_t)(b * SEQ + s) * HID;
  float v[12];
  float u1p = 0.0f;
#pragma unroll
  for (int jj = 0; jj < 12; jj++) {
    int d = l + 64 * jj;
    float x = hrow[d];
    u1p += x * attn_w[d];
    v[jj] = attn_w[HID + d] + x * attn_w[2 * HID + d];
  }
  float u1 = wred(u1p) + attn_b[0];
  float sc[21];
  for (int o = 0; o < 21; o++) {
    int s2 = s + o - 10;
    if (s2 >= 0 && s2 < SEQ) {
      const float* h2 = hs + (size_t)(b * SEQ + s2) * HID;
      float p = 0.0f;
#pragma unroll
      for (int jj = 0; jj < 12; jj++) p += h2[l + 64 * jj] * v[jj];
      sc[o] = wred(p) + u1;
    } else {
      sc[o] = NEGV;
    }
  }
  float m = sc[0];
#pragma unroll
  for (int o = 1; o < 21; o++) m = fmaxf(m, sc[o]);
  float sum = 0.0f;
#pragma unroll
  for (int o = 0; o < 21; o++) { sc[o] = expf(sc[o] - m); sum += sc[o]; }
  float inv = 1.0f / sum;
  float acc[12];
#pragma unroll
  for (int jj = 0; jj < 12; jj++) acc[jj] = 0.0f;
  for (int o = 0; o < 21; o++) {
    int s2 = s + o - 10;
    if (s2 < 0 || s2 >= SEQ) continue;
    float a = sc[o] * inv;
    const float* h2 = hs + (size_t)(b * SEQ + s2) * HID;
#pragma unroll
    for (int jj = 0; jj < 12; jj++) acc[jj] += a * h2[l + 64 * jj];
  }
  float* orow = att + (size_t)(b * SEQ + s) * HID;
#pragma unroll
  for (int jj = 0; jj < 12; jj++) orow[l + 64 * jj] = acc[jj];
}

// -------------------------------------------------------- L2 input projection
__global__ __launch_bounds__(256) void k_proj2(
    const float* __restrict__ hs, const float* __restrict__ att,
    const float* __restrict__ w2f, const float* __restrict__ b2f,
    const float* __restrict__ w2r, const float* __restrict__ b2r,
    float* __restrict__ xs2) {
  __shared__ __align__(16) float x2[2 * HID];
  __shared__ float part[32][9];
  const int tid = threadIdx.x;
  const int s = blockIdx.x, b = blockIdx.y;
  size_t base = (size_t)(b * SEQ + s) * HID;
  for (int i = tid; i < 2 * HID; i += 256)
    x2[i] = (i < HID) ? hs[base + i] : att[base + i - HID];
  __syncthreads();
  const int gid = tid & 31, pp = tid >> 5;
  const int d = gid >> 4, g = gid & 15;
  const float4* w4 = (const float4*)((d ? w2r : w2f) + (size_t)g * (2 * HID));
  const float4* x4 = (const float4*)x2;
  float p = 0.0f;
  for (int e = pp * 48; e < pp * 48 + 48; e++) {
    float4 xv = x4[e];
    float4 wv = w4[e];
    p += xv.x * wv.x + xv.y * wv.y + xv.z * wv.z + xv.w * wv.w;
  }
  part[gid][pp] = p;
  __syncthreads();
  if (tid < 32) {
    float sumv = (d ? b2r : b2f)[g];
#pragma unroll
    for (int q = 0; q < 8; q++) sumv += part[gid][q];
    xs2[(size_t)((d * BATCH + b) * SEQ + s) * 16 + g] = sumv;
  }
}

// ------------------------------------------------------------- L2 recurrence
// Wave-local: each (dir,batch) combo lives in 16 lanes of one wave;
// h exchanged by shfl (no __syncthreads, no LDS). xs2 load software-pipelined
// one step ahead so its L2 latency hides under the gate math.
__global__ __launch_bounds__(256) void k_rec2(
    const float* __restrict__ xs2,
    const float* __restrict__ whh_f, const float* __restrict__ whh_r,
    float* __restrict__ h2) {
  const int tid = threadIdx.x;
  const int lane = tid & 63;
  const int hb = (tid >> 6) * 4 + (lane >> 4);   // 0..15 = dir*8 + b
  const int g = lane & 15;
  const int d = hb >> 3;
  const int base = lane & 48;                     // first lane of my 16-lane group
  const float* whh = (d ? whh_r : whh_f) + g * 4;
  const float w0 = whh[0], w1 = whh[1], w2 = whh[2], w3 = whh[3];
  const float* xrow = xs2 + (size_t)hb * SEQ * 16 + g;
  float c = 0.0f, h = 0.0f;
  float xv = xrow[(d ? (SEQ - 1) : 0) * 16];
  for (int st = 0; st < SEQ; st++) {
    const int t = d ? (SEQ - 1 - st) : st;
    const int tn = d ? (SEQ - 2 - st) : (st + 1);
    float xnext = (st + 1 < SEQ) ? xrow[tn * 16] : 0.0f;
    float h0 = __shfl(h, base + 0, 64);
    float h1 = __shfl(h, base + 1, 64);
    float h2v = __shfl(h, base + 2, 64);
    float h3 = __shfl(h, base + 3, 64);
    float gv = xv + w0 * h0 + w1 * h1 + w2 * h2v + w3 * h3;
    const int jj = g & 3;
    float iv = __shfl(gv, base + jj, 64);
    float fv = __shfl(gv, base + 4 + jj, 64);
    float gq = __shfl(gv, base + 8 + jj, 64);
    float ov = __shfl(gv, base + 12 + jj, 64);
    c = sigm(fv) * c + sigm(iv) * tanhf(gq);
    h = sigm(ov) * tanhf(c);
    if (g < 4) h2[((size_t)hb * SEQ + t) * 4 + g] = h;
    xv = xnext;
  }
}

// ------------------------------------------------------------------ em = f+r
__global__ void k_em(const float* __restrict__ h2, float* __restrict__ out) {
  int i = blockIdx.x * 256 + threadIdx.x;
  if (i < BATCH * SEQ * 4) out[BATCH * SEQ + i] = h2[i] + h2[BATCH * SEQ * 4 + i];
}

// ------------------------------------------------------------------- viterbi
__global__ __launch_bounds__(32) void k_viterbi(
    float* __restrict__ out, const float* __restrict__ start,
    const float* __restrict__ endw, const float* __restrict__ trans) {
  __shared__ unsigned char bp[SEQ - 1][32];
  const int l = threadIdx.x;
  const int b = l >> 2, j = l & 3;
  const float* em = out + BATCH * SEQ;
  const float tr0 = trans[0 * 4 + j], tr1 = trans[1 * 4 + j];
  const float tr2 = trans[2 * 4 + j], tr3 = trans[3 * 4 + j];
  float score = start[j] + em[((size_t)b * SEQ + 0) * 4 + j];
  for (int t = 1; t < SEQ; t++) {
    float s0 = __shfl(score, b * 4 + 0, 64);
    float s1 = __shfl(score, b * 4 + 1, 64);
    float s2 = __shfl(score, b * 4 + 2, 64);
    float s3 = __shfl(score, b * 4 + 3, 64);
    float v0 = s0 + tr0, v1 = s1 + tr1, v2 = s2 + tr2, v3 = s3 + tr3;
    float best = v0; int arg = 0;
    if (v1 > best) { best = v1; arg = 1; }
    if (v2 > best) { best = v2; arg = 2; }
    if (v3 > best) { best = v3; arg = 3; }
    bp[t - 1][l] = (unsigned char)arg;
    score = best + em[((size_t)b * SEQ + t) * 4 + j];
  }
  score += endw[j];
  float f0 = __shfl(score, b * 4 + 0, 64);
  float f1 = __shfl(score, b * 4 + 1, 64);
  float f2 = __shfl(score, b * 4 + 2, 64);
  float f3 = __shfl(score, b * 4 + 3, 64);
  if (j == 0) {
    float bbv = f0; int last = 0;
    if (f1 > bbv) { bbv = f1; last = 1; }
    if (f2 > bbv) { bbv = f2; last = 2; }
    if (f3 > bbv) { bbv = f3; last = 3; }
    int tag = last;
    out[b * SEQ + (SEQ - 1)] = (float)tag;
    for (int t = SEQ - 2; t >= 0; t--) {
      tag = bp[t][b * 4 + tag];
      out[b * SEQ + t] = (float)tag;
    }
  }
}

// ------------------------------------------------------------------ launcher
extern "C" void kernel_launch(void* const* d_in, const int* in_sizes, int n_in,
                              void* d_out, int out_size, void* d_ws, size_t ws_size,
                              hipStream_t stream) {
  const float* emb      = (const float*)d_in[0];
  const float* l1f_wih  = (const float*)d_in[1];
  const float* l1f_whh  = (const float*)d_in[2];
  const float* l1f_b    = (const float*)d_in[3];
  const float* l1r_wih  = (const float*)d_in[4];
  const float* l1r_whh  = (const float*)d_in[5];
  const float* l1r_b    = (const float*)d_in[6];
  const float* attn_w   = (const float*)d_in[7];
  const float* attn_b   = (const float*)d_in[8];
  const float* l2f_wih  = (const float*)d_in[9];
  const float* l2f_whh  = (const float*)d_in[10];
  const float* l2f_b    = (const float*)d_in[11];
  const float* l2r_wih  = (const float*)d_in[12];
  const float* l2r_whh  = (const float*)d_in[13];
  const float* l2r_b    = (const float*)d_in[14];
  const float* crf_start= (const float*)d_in[15];
  const float* crf_end  = (const float*)d_in[16];
  const float* crf_trans= (const float*)d_in[17];

  float* ws = (float*)d_ws;
  const size_t NCH = (size_t)BATCH * CHUNK * G4;     // 3,145,728 floats
  float* xs_f = ws;
  float* xs_r = xs_f + NCH;
  float* hf   = xs_r + NCH;                          // [b][t][HID]
  float* hr   = hf + (size_t)BATCH * SEQ * HID;
  float* hbuf = hr + (size_t)BATCH * SEQ * HID;      // 24,576 floats
  float* cbuf = hbuf + 2 * 2 * BATCH * HID;          // 12,288 floats
  float* h2   = cbuf + 256 * 48;                     // 32,768 floats
  int*   flags= (int*)(h2 + 2 * BATCH * SEQ * 4);    // 4,096 ints (padded)
  float* xs2  = xs_f;                                // overlay
  float* att  = xs_r;                                // overlay
  float* hs   = hf;                                  // after k_sum, hf = hf+hr

  k_init<<<dim3(96), dim3(256), 0, stream>>>(hbuf, flags);

  for (int c = 0; c < 4; c++) {
    k_proj1<<<dim3(24, 8, 2), dim3(256), 0, stream>>>(
        emb, l1f_wih, l1f_b, l1r_wih, l1r_b, xs_f, xs_r, c);
    k_rec1<<<dim3(128), dim3(768), 0, stream>>>(
        l1f_whh, l1r_whh, xs_f, xs_r, hbuf, cbuf, flags, hf, hr,
        c * CHUNK, c == 0 ? 1 : 0);
  }

  k_sum<<<dim3(3072), dim3(256), 0, stream>>>(hf, hr);
  k_attn<<<dim3(SEQ, BATCH), dim3(64), 0, stream>>>(hs, attn_w, attn_b, att);
  k_proj2<<<dim3(SEQ, BATCH), dim3(256), 0, stream>>>(
      hs, att, l2f_wih, l2f_b, l2r_wih, l2r_b, xs2);
  k_rec2<<<dim3(1), dim3(256), 0, stream>>>(xs2, l2f_whh, l2r_whh, h2);
  k_em<<<dim3(64), dim3(256), 0, stream>>>(h2, (float*)d_out);
  k_viterbi<<<dim3(1), dim3(32), 0, stream>>>((float*)d_out, crf_start, crf_end, crf_trans);
}

// Round 10
// 3640.682 us; speedup vs baseline: 1.3634x; 1.3634x over previous
//
#include <hip/hip_runtime.h>
#include <math.h>

#define SEQ 512
#define BATCH 8
#define HID 768
#define G4 3072           // 4*HID
#define CHUNK 128
#define NEGV (-1000000000.0f)

typedef float v4f __attribute__((ext_vector_type(4)));
typedef float v2f __attribute__((ext_vector_type(2)));

__device__ __forceinline__ float sigm(float x) { return 1.0f / (1.0f + expf(-x)); }

// packed fp32 fma (v_pk_fma_f32 on CDNA); fma semantics match the compiler's
// default contraction of a*b+c, so numerics are identical to the scalar code.
__device__ __forceinline__ v2f fma2(v2f a, v2f b, v2f c) {
#if __has_builtin(__builtin_elementwise_fma)
  return __builtin_elementwise_fma(a, b, c);
#else
  v2f r; r.x = __builtin_fmaf(a.x, b.x, c.x); r.y = __builtin_fmaf(a.y, b.y, c.y);
  return r;
#endif
}

__device__ __forceinline__ float wred(float x) {
#pragma unroll
  for (int off = 32; off > 0; off >>= 1) x += __shfl_xor(x, off, 64);
  return x;
}

// ---- device-coherent (bypass L1+L2) memory ops: always correct cross-XCD ----
__device__ __forceinline__ void load2_f4_sc(const float* p0, const float* p1,
                                            v4f& a, v4f& b) {
  asm volatile("global_load_dwordx4 %0, %2, off sc0 sc1\n\t"
               "global_load_dwordx4 %1, %3, off sc0 sc1\n\t"
               "s_waitcnt vmcnt(0)"
               : "=&v"(a), "=&v"(b) : "v"(p0), "v"(p1) : "memory");
}
__device__ __forceinline__ int load_i_sc(const int* p) {
  int r;
  asm volatile("global_load_dword %0, %1, off sc0 sc1\n\ts_waitcnt vmcnt(0)"
               : "=v"(r) : "v"(p) : "memory");
  return r;
}
__device__ __forceinline__ void store_f_sc(float* p, float v) {
  asm volatile("global_store_dword %0, %1, off sc0 sc1" :: "v"(p), "v"(v) : "memory");
}
__device__ __forceinline__ void store_i_sc(int* p, int v) {
  asm volatile("global_store_dword %0, %1, off sc0 sc1" :: "v"(p), "v"(v) : "memory");
}

// ---- VALU-pipe 32-lane reduction: 4x row_ror (row sums) + row_bcast15 ----
template <int CTRL, int RMASK>
__device__ __forceinline__ float dpp_add(float x) {
  int y = __builtin_amdgcn_update_dpp(0, __float_as_int(x), CTRL, RMASK, 0xF, false);
  return x + __int_as_float(y);
}
__device__ __forceinline__ float reduce32(float x) {
  x = dpp_add<0x121, 0xF>(x);  // row_ror:1
  x = dpp_add<0x122, 0xF>(x);  // row_ror:2
  x = dpp_add<0x124, 0xF>(x);  // row_ror:4
  x = dpp_add<0x128, 0xF>(x);  // row_ror:8  -> every lane holds its 16-row sum
  x = dpp_add<0x142, 0xA>(x);  // row_bcast15 into rows 1,3 -> kq>=16 = 32-sum
  return x;
}

// ---------------------------------------------------------------- init zeros
// flags are PADDED: one 64B line per flag -> flags[(grp*64+jb)*16]
__global__ void k_init(float* __restrict__ hbuf, int* __restrict__ flags) {
  int i = blockIdx.x * blockDim.x + threadIdx.x;
  if (i < 2 * 2 * BATCH * HID) hbuf[i] = 0.0f;   // [par][dir][b][HID]
  if (i < 4096) flags[i] = 0;                    // 256 flags x 16-int pad
}

// ------------------------------------------- L1 input projection, one chunk
// Round-8 single-tile register prefetch + Round-9 intra-row LDS padding:
// col c -> c + ((c>>5)<<2) breaks the 4-way read conflict on As[k][tm*8]
// (banks {0,8,16,24}x4 -> 9*tm-spaced, <=2-way = free per m136). Pure layout
// change; bitwise-identical numerics. (Round-7 lambda dbuf spilled: avoid.)
#define CMAP(c) ((c) + (((c) >> 5) << 2))
__global__ __launch_bounds__(256) void k_proj1(
    const float* __restrict__ emb,
    const float* __restrict__ w_f, const float* __restrict__ b_f,
    const float* __restrict__ w_r, const float* __restrict__ b_r,
    float* __restrict__ xs_f, float* __restrict__ xs_r, int chunk) {
  __shared__ float As[16][144];
  __shared__ float Bs[16][144];
  const int tid = threadIdx.x;
  const int bn0 = blockIdx.x * 128;
  const int bb  = blockIdx.y;
  const int dir = blockIdx.z;
  const float* W    = dir ? w_r : w_f;
  const float* bias = dir ? b_r : b_f;
  float* xs = dir ? xs_r : xs_f;

  v2f acc2[8][4];
#pragma unroll
  for (int i = 0; i < 8; i++)
#pragma unroll
    for (int j = 0; j < 4; j++) acc2[i][j] = (v2f){0.0f, 0.0f};

  const int mload = tid & 127;
  const int kq0   = tid >> 7;
  const int tglob = dir ? (SEQ - 1 - (chunk * CHUNK + mload)) : (chunk * CHUNK + mload);
  const float* arow = emb + (size_t)(bb * SEQ + tglob) * HID;
  const float* brow = W + (size_t)(bn0 + mload) * HID;
  const int tm = tid & 15, tn = tid >> 4;
  const int cw = CMAP(mload);            // swizzled write column
  const int cA = CMAP(tm * 8);           // swizzled read col base (A)
  const int cB = CMAP(tn * 8);           // swizzled read col base (B)

  // per-thread load cursors: rep0 at +0, rep1 at +8 floats (kq = kq0, kq0+2)
  const float* aptr = arow + kq0 * 4;
  const float* bptr = brow + kq0 * 4;
  const int rA = kq0 * 4;          // LDS row base, rep0
  const int rB = (kq0 + 2) * 4;    // LDS row base, rep1

  // prologue: tile 0 -> regs
  float4 a0 = *(const float4*)(aptr);
  float4 a1 = *(const float4*)(aptr + 8);
  float4 b0 = *(const float4*)(bptr);
  float4 b1 = *(const float4*)(bptr + 8);

  for (int kt = 0; kt < HID; kt += 16) {
    // stage current tile regs -> LDS
    As[rA + 0][cw] = a0.x; As[rA + 1][cw] = a0.y;
    As[rA + 2][cw] = a0.z; As[rA + 3][cw] = a0.w;
    As[rB + 0][cw] = a1.x; As[rB + 1][cw] = a1.y;
    As[rB + 2][cw] = a1.z; As[rB + 3][cw] = a1.w;
    Bs[rA + 0][cw] = b0.x; Bs[rA + 1][cw] = b0.y;
    Bs[rA + 2][cw] = b0.z; Bs[rA + 3][cw] = b0.w;
    Bs[rB + 0][cw] = b1.x; Bs[rB + 1][cw] = b1.y;
    Bs[rB + 2][cw] = b1.z; Bs[rB + 3][cw] = b1.w;
    __syncthreads();
    // prefetch next tile (latency spans the compute below)
    if (kt + 16 < HID) {
      a0 = *(const float4*)(aptr + kt + 16);
      a1 = *(const float4*)(aptr + kt + 24);
      b0 = *(const float4*)(bptr + kt + 16);
      b1 = *(const float4*)(bptr + kt + 24);
    }
#pragma unroll
    for (int k = 0; k < 16; k++) {
      float4 c0 = *(const float4*)&As[k][cA];
      float4 c1 = *(const float4*)&As[k][cA + 4];
      float4 d0 = *(const float4*)&Bs[k][cB];
      float4 d1 = *(const float4*)&Bs[k][cB + 4];
      float av[8] = {c0.x, c0.y, c0.z, c0.w, c1.x, c1.y, c1.z, c1.w};
      v2f bv2[4] = {{d0.x, d0.y}, {d0.z, d0.w}, {d1.x, d1.y}, {d1.z, d1.w}};
#pragma unroll
      for (int i = 0; i < 8; i++) {
        v2f avv = {av[i], av[i]};
#pragma unroll
        for (int jj = 0; jj < 4; jj++) acc2[i][jj] = fma2(avv, bv2[jj], acc2[i][jj]);
      }
    }
    __syncthreads();
  }
#pragma unroll
  for (int i = 0; i < 8; i++) {
    int row = tm * 8 + i;
    size_t base = (size_t)(bb * CHUNK + row) * G4 + bn0 + tn * 8;
#pragma unroll
    for (int jj = 0; jj < 4; jj++) {
      xs[base + 2 * jj]     = acc2[i][jj].x + bias[bn0 + tn * 8 + 2 * jj];
      xs[base + 2 * jj + 1] = acc2[i][jj].y + bias[bn0 + tn * 8 + 2 * jj + 1];
    }
  }
}

// ---------------------------------------- L1 recurrence: persistent kernel
// ROUND-8 FORM RESTORED VERBATIM — verified 648us. 256 blocks x 384 threads.
// CLOSED after round 9: block-geometry perturbations all regress —
//   fused proj (r1/r2): 888-909; packet protocol (r6): 975;
//   128x768 (r9): 1025 (12-wave barrier straggler tail + half the CUs;
//   FETCH dropped 25% yet time rose 58% -> traffic is NOT the bottleneck).
// The ~5us/step = ~1.2us compute + ~3.8us cross-XCD publication chain at
// 256x384 is this protocol's floor.
// ROUND-4: scalar dot chains (chain depth rules a serial chain).
// ROUND-8: harr history stores deferred past flag publication (free).
__global__ __launch_bounds__(384, 2) void k_rec1(
    const float* __restrict__ whh_f, const float* __restrict__ whh_r,
    const float* __restrict__ xs_f, const float* __restrict__ xs_r,
    float* __restrict__ hbuf, float* __restrict__ cbuf, int* __restrict__ flags,
    float* __restrict__ hf, float* __restrict__ hr, int t0, int init) {
  __shared__ float hlds[4 * HID];
  const int tid = threadIdx.x;
  const int bid = blockIdx.x;
  const int dir = bid >> 7;
  const int bh  = (bid >> 6) & 1;
  const int jb  = bid & 63;
  const int J0  = jb * 12;
  const int grp = dir * 2 + bh;
  const int g  = tid >> 5;
  const int kq = tid & 31;
  const int j  = J0 + g;

  const float* W  = dir ? whh_r : whh_f;
  const float* xs = dir ? xs_r  : xs_f;
  float* harr = dir ? hr : hf;

  // W_hh slice -> registers (once per chunk launch), interleaved k layout
  float wreg[4][24];
#pragma unroll
  for (int gate = 0; gate < 4; gate++) {
#pragma unroll
    for (int q = 0; q < 6; q++) {
      *(v4f*)&wreg[gate][q * 4] =
          *(const v4f*)&W[(size_t)(gate * HID + j) * HID + q * 128 + kq * 4];
    }
  }

  float cc[4];
#pragma unroll
  for (int b = 0; b < 4; b++) cc[b] = 0.0f;
  if (!init && kq == 16) {
#pragma unroll
    for (int b = 0; b < 4; b++) cc[b] = cbuf[bid * 48 + g * 4 + b];
  }

  for (int stp = 0; stp < CHUNK; stp++) {
    const int s = t0 + stp;
    const int par = s & 1;

    // prefetch xs gate values for writers BEFORE the wait (cached loads;
    // cannot sink past the asm memory clobbers in the poll loop)
    float xsv[4][4];
    if (kq == 16) {
#pragma unroll
      for (int b = 0; b < 4; b++) {
        const size_t xbase = (size_t)((bh * 4 + b) * CHUNK + stp) * G4 + j;
#pragma unroll
        for (int gate = 0; gate < 4; gate++)
          xsv[b][gate] = xs[xbase + gate * HID];
      }
    }

    // wait until all 64 blocks of this group published h_{s-1}
    if (tid < 64) {
      const int* fp = flags + (grp * 64 + tid) * 16;   // one line per flag
      while (load_i_sc(fp) < s) { __builtin_amdgcn_s_sleep(4); }
    }
    __syncthreads();

    // stage h_{s-1} (my dir, my 4 b's) into LDS
    {
      const float* src = hbuf + (size_t)((par * 2 + dir) * BATCH + bh * 4) * HID + tid * 8;
      v4f a, b4;
      load2_f4_sc(src, src + 4, a, b4);
      *(v4f*)&hlds[tid * 8]     = a;
      *(v4f*)&hlds[tid * 8 + 4] = b4;
    }
    __syncthreads();

    // dots: 4 gates x 4 b over this thread's interleaved k-slice
    float acc[4][4];
#pragma unroll
    for (int gate = 0; gate < 4; gate++)
#pragma unroll
      for (int b = 0; b < 4; b++) acc[gate][b] = 0.0f;
#pragma unroll
    for (int b = 0; b < 4; b++) {
      float hk[24];
#pragma unroll
      for (int q = 0; q < 6; q++)
        *(v4f*)&hk[q * 4] = *(const v4f*)&hlds[b * HID + q * 128 + kq * 4];
#pragma unroll
      for (int gate = 0; gate < 4; gate++)
#pragma unroll
        for (int k = 0; k < 24; k++) acc[gate][b] += wreg[gate][k] * hk[k];
    }
#pragma unroll
    for (int gate = 0; gate < 4; gate++)
#pragma unroll
      for (int b = 0; b < 4; b++) acc[gate][b] = reduce32(acc[gate][b]);

    // writers: LSTM pointwise + publish h (sc stores only on publish path)
    float hv[4];
    int t = 0;
    if (kq == 16) {
      t = dir ? (SEQ - 1 - s) : s;
#pragma unroll
      for (int b = 0; b < 4; b++) {
        const int bg = bh * 4 + b;
        float iv = acc[0][b] + xsv[b][0];
        float fv = acc[1][b] + xsv[b][1];
        float gv = acc[2][b] + xsv[b][2];
        float ov = acc[3][b] + xsv[b][3];
        cc[b] = sigm(fv) * cc[b] + sigm(iv) * tanhf(gv);
        hv[b] = sigm(ov) * tanhf(cc[b]);
        store_f_sc(hbuf + (size_t)(((par ^ 1) * 2 + dir) * BATCH + bg) * HID + j, hv[b]);
      }
    }
    asm volatile("s_waitcnt vmcnt(0)" ::: "memory");
    __syncthreads();
    if (tid == 0) store_i_sc(flags + (grp * 64 + jb) * 16, s + 1);
    // deferred history stores: off the publication critical path
    if (kq == 16) {
#pragma unroll
      for (int b = 0; b < 4; b++)
        harr[(size_t)((bh * 4 + b) * SEQ + t) * HID + j] = hv[b];
    }
  }
  if (kq == 16) {
#pragma unroll
    for (int b = 0; b < 4; b++) cbuf[bid * 48 + g * 4 + b] = cc[b];
  }
}

// ----------------------------------------------------------- hs = hf + hr
__global__ void k_sum(float* __restrict__ hf, const float* __restrict__ hr) {
  int i = blockIdx.x * 256 + threadIdx.x;
  float4 a = ((const float4*)hf)[i];
  float4 b = ((const float4*)hr)[i];
  a.x += b.x; a.y += b.y; a.z += b.z; a.w += b.w;
  ((float4*)hf)[i] = a;
}

// --------------------------------------------------------- windowed attention
__global__ __launch_bounds__(64) void k_attn(
    const float* __restrict__ hs, const float* __restrict__ attn_w,
    const float* __restrict__ attn_b, float* __restrict__ att) {
  const int l = threadIdx.x;
  const int s = blockIdx.x, b = blockIdx.y;
  const float* hrow = hs + (size_t)(b * SEQ + s) * HID;
  float v[12];
  float u1p = 0.0f;
#pragma unroll
  for (int jj = 0; jj < 12; jj++) {
    int d = l + 64 * jj;
    float x = hrow[d];
    u1p += x * attn_w[d];
    v[jj] = attn_w[HID + d] + x * attn_w[2 * HID + d];
  }
  float u1 = wred(u1p) + attn_b[0];
  float sc[21];
  for (int o = 0; o < 21; o++) {
    int s2 = s + o - 10;
    if (s2 >= 0 && s2 < SEQ) {
      const float* h2 = hs + (size_t)(b * SEQ + s2) * HID;
      float p = 0.0f;
#pragma unroll
      for (int jj = 0; jj < 12; jj++) p += h2[l + 64 * jj] * v[jj];
      sc[o] = wred(p) + u1;
    } else {
      sc[o] = NEGV;
    }
  }
  float m = sc[0];
#pragma unroll
  for (int o = 1; o < 21; o++) m = fmaxf(m, sc[o]);
  float sum = 0.0f;
#pragma unroll
  for (int o = 0; o < 21; o++) { sc[o] = expf(sc[o] - m); sum += sc[o]; }
  float inv = 1.0f / sum;
  float acc[12];
#pragma unroll
  for (int jj = 0; jj < 12; jj++) acc[jj] = 0.0f;
  for (int o = 0; o < 21; o++) {
    int s2 = s + o - 10;
    if (s2 < 0 || s2 >= SEQ) continue;
    float a = sc[o] * inv;
    const float* h2 = hs + (size_t)(b * SEQ + s2) * HID;
#pragma unroll
    for (int jj = 0; jj < 12; jj++) acc[jj] += a * h2[l + 64 * jj];
  }
  float* orow = att + (size_t)(b * SEQ + s) * HID;
#pragma unroll
  for (int jj = 0; jj < 12; jj++) orow[l + 64 * jj] = acc[jj];
}

// -------------------------------------------------------- L2 input projection
__global__ __launch_bounds__(256) void k_proj2(
    const float* __restrict__ hs, const float* __restrict__ att,
    const float* __restrict__ w2f, const float* __restrict__ b2f,
    const float* __restrict__ w2r, const float* __restrict__ b2r,
    float* __restrict__ xs2) {
  __shared__ __align__(16) float x2[2 * HID];
  __shared__ float part[32][9];
  const int tid = threadIdx.x;
  const int s = blockIdx.x, b = blockIdx.y;
  size_t base = (size_t)(b * SEQ + s) * HID;
  for (int i = tid; i < 2 * HID; i += 256)
    x2[i] = (i < HID) ? hs[base + i] : att[base + i - HID];
  __syncthreads();
  const int gid = tid & 31, pp = tid >> 5;
  const int d = gid >> 4, g = gid & 15;
  const float4* w4 = (const float4*)((d ? w2r : w2f) + (size_t)g * (2 * HID));
  const float4* x4 = (const float4*)x2;
  float p = 0.0f;
  for (int e = pp * 48; e < pp * 48 + 48; e++) {
    float4 xv = x4[e];
    float4 wv = w4[e];
    p += xv.x * wv.x + xv.y * wv.y + xv.z * wv.z + xv.w * wv.w;
  }
  part[gid][pp] = p;
  __syncthreads();
  if (tid < 32) {
    float sumv = (d ? b2r : b2f)[g];
#pragma unroll
    for (int q = 0; q < 8; q++) sumv += part[gid][q];
    xs2[(size_t)((d * BATCH + b) * SEQ + s) * 16 + g] = sumv;
  }
}

// ------------------------------------------------------------- L2 recurrence
// Wave-local: each (dir,batch) combo lives in 16 lanes of one wave;
// h exchanged by shfl (no __syncthreads, no LDS). xs2 load software-pipelined
// one step ahead so its L2 latency hides under the gate math.
__global__ __launch_bounds__(256) void k_rec2(
    const float* __restrict__ xs2,
    const float* __restrict__ whh_f, const float* __restrict__ whh_r,
    float* __restrict__ h2) {
  const int tid = threadIdx.x;
  const int lane = tid & 63;
  const int hb = (tid >> 6) * 4 + (lane >> 4);   // 0..15 = dir*8 + b
  const int g = lane & 15;
  const int d = hb >> 3;
  const int base = lane & 48;                     // first lane of my 16-lane group
  const float* whh = (d ? whh_r : whh_f) + g * 4;
  const float w0 = whh[0], w1 = whh[1], w2 = whh[2], w3 = whh[3];
  const float* xrow = xs2 + (size_t)hb * SEQ * 16 + g;
  float c = 0.0f, h = 0.0f;
  float xv = xrow[(d ? (SEQ - 1) : 0) * 16];
  for (int st = 0; st < SEQ; st++) {
    const int t = d ? (SEQ - 1 - st) : st;
    const int tn = d ? (SEQ - 2 - st) : (st + 1);
    float xnext = (st + 1 < SEQ) ? xrow[tn * 16] : 0.0f;
    float h0 = __shfl(h, base + 0, 64);
    float h1 = __shfl(h, base + 1, 64);
    float h2v = __shfl(h, base + 2, 64);
    float h3 = __shfl(h, base + 3, 64);
    float gv = xv + w0 * h0 + w1 * h1 + w2 * h2v + w3 * h3;
    const int jj = g & 3;
    float iv = __shfl(gv, base + jj, 64);
    float fv = __shfl(gv, base + 4 + jj, 64);
    float gq = __shfl(gv, base + 8 + jj, 64);
    float ov = __shfl(gv, base + 12 + jj, 64);
    c = sigm(fv) * c + sigm(iv) * tanhf(gq);
    h = sigm(ov) * tanhf(c);
    if (g < 4) h2[((size_t)hb * SEQ + t) * 4 + g] = h;
    xv = xnext;
  }
}

// ------------------------------------------------------------------ em = f+r
__global__ void k_em(const float* __restrict__ h2, float* __restrict__ out) {
  int i = blockIdx.x * 256 + threadIdx.x;
  if (i < BATCH * SEQ * 4) out[BATCH * SEQ + i] = h2[i] + h2[BATCH * SEQ * 4 + i];
}

// ------------------------------------------------------------------- viterbi
__global__ __launch_bounds__(32) void k_viterbi(
    float* __restrict__ out, const float* __restrict__ start,
    const float* __restrict__ endw, const float* __restrict__ trans) {
  __shared__ unsigned char bp[SEQ - 1][32];
  const int l = threadIdx.x;
  const int b = l >> 2, j = l & 3;
  const float* em = out + BATCH * SEQ;
  const float tr0 = trans[0 * 4 + j], tr1 = trans[1 * 4 + j];
  const float tr2 = trans[2 * 4 + j], tr3 = trans[3 * 4 + j];
  float score = start[j] + em[((size_t)b * SEQ + 0) * 4 + j];
  for (int t = 1; t < SEQ; t++) {
    float s0 = __shfl(score, b * 4 + 0, 64);
    float s1 = __shfl(score, b * 4 + 1, 64);
    float s2 = __shfl(score, b * 4 + 2, 64);
    float s3 = __shfl(score, b * 4 + 3, 64);
    float v0 = s0 + tr0, v1 = s1 + tr1, v2 = s2 + tr2, v3 = s3 + tr3;
    float best = v0; int arg = 0;
    if (v1 > best) { best = v1; arg = 1; }
    if (v2 > best) { best = v2; arg = 2; }
    if (v3 > best) { best = v3; arg = 3; }
    bp[t - 1][l] = (unsigned char)arg;
    score = best + em[((size_t)b * SEQ + t) * 4 + j];
  }
  score += endw[j];
  float f0 = __shfl(score, b * 4 + 0, 64);
  float f1 = __shfl(score, b * 4 + 1, 64);
  float f2 = __shfl(score, b * 4 + 2, 64);
  float f3 = __shfl(score, b * 4 + 3, 64);
  if (j == 0) {
    float bbv = f0; int last = 0;
    if (f1 > bbv) { bbv = f1; last = 1; }
    if (f2 > bbv) { bbv = f2; last = 2; }
    if (f3 > bbv) { bbv = f3; last = 3; }
    int tag = last;
    out[b * SEQ + (SEQ - 1)] = (float)tag;
    for (int t = SEQ - 2; t >= 0; t--) {
      tag = bp[t][b * 4 + tag];
      out[b * SEQ + t] = (float)tag;
    }
  }
}

// ------------------------------------------------------------------ launcher
extern "C" void kernel_launch(void* const* d_in, const int* in_sizes, int n_in,
                              void* d_out, int out_size, void* d_ws, size_t ws_size,
                              hipStream_t stream) {
  const float* emb      = (const float*)d_in[0];
  const float* l1f_wih  = (const float*)d_in[1];
  const float* l1f_whh  = (const float*)d_in[2];
  const float* l1f_b    = (const float*)d_in[3];
  const float* l1r_wih  = (const float*)d_in[4];
  const float* l1r_whh  = (const float*)d_in[5];
  const float* l1r_b    = (const float*)d_in[6];
  const float* attn_w   = (const float*)d_in[7];
  const float* attn_b   = (const float*)d_in[8];
  const float* l2f_wih  = (const float*)d_in[9];
  const float* l2f_whh  = (const float*)d_in[10];
  const float* l2f_b    = (const float*)d_in[11];
  const float* l2r_wih  = (const float*)d_in[12];
  const float* l2r_whh  = (const float*)d_in[13];
  const float* l2r_b    = (const float*)d_in[14];
  const float* crf_start= (const float*)d_in[15];
  const float* crf_end  = (const float*)d_in[16];
  const float* crf_trans= (const float*)d_in[17];

  float* ws = (float*)d_ws;
  const size_t NCH = (size_t)BATCH * CHUNK * G4;     // 3,145,728 floats
  float* xs_f = ws;
  float* xs_r = xs_f + NCH;
  float* hf   = xs_r + NCH;                          // [b][t][HID]
  float* hr   = hf + (size_t)BATCH * SEQ * HID;
  float* hbuf = hr + (size_t)BATCH * SEQ * HID;      // 24,576 floats
  float* cbuf = hbuf + 2 * 2 * BATCH * HID;          // 12,288 floats
  float* h2   = cbuf + 256 * 48;                     // 32,768 floats
  int*   flags= (int*)(h2 + 2 * BATCH * SEQ * 4);    // 4,096 ints (padded)
  float* xs2  = xs_f;                                // overlay
  float* att  = xs_r;                                // overlay
  float* hs   = hf;                                  // after k_sum, hf = hf+hr

  k_init<<<dim3(96), dim3(256), 0, stream>>>(hbuf, flags);

  for (int c = 0; c < 4; c++) {
    k_proj1<<<dim3(24, 8, 2), dim3(256), 0, stream>>>(
        emb, l1f_wih, l1f_b, l1r_wih, l1r_b, xs_f, xs_r, c);
    k_rec1<<<dim3(256), dim3(384), 0, stream>>>(
        l1f_whh, l1r_whh, xs_f, xs_r, hbuf, cbuf, flags, hf, hr,
        c * CHUNK, c == 0 ? 1 : 0);
  }

  k_sum<<<dim3(3072), dim3(256), 0, stream>>>(hf, hr);
  k_attn<<<dim3(SEQ, BATCH), dim3(64), 0, stream>>>(hs, attn_w, attn_b, att);
  k_proj2<<<dim3(SEQ, BATCH), dim3(256), 0, stream>>>(
      hs, att, l2f_wih, l2f_b, l2r_wih, l2r_b, xs2);
  k_rec2<<<dim3(1), dim3(256), 0, stream>>>(xs2, l2f_whh, l2r_whh, h2);
  k_em<<<dim3(64), dim3(256), 0, stream>>>(h2, (float*)d_out);
  k_viterbi<<<dim3(1), dim3(32), 0, stream>>>((float*)d_out, crf_start, crf_end, crf_trans);
}

// Round 11
// 3589.516 us; speedup vs baseline: 1.3828x; 1.0143x over previous
//
#include <hip/hip_runtime.h>
#include <math.h>

#define SEQ 512
#define BATCH 8
#define HID 768
#define G4 3072           // 4*HID
#define CHUNK 128
#define NEGV (-1000000000.0f)

typedef float v4f __attribute__((ext_vector_type(4)));
typedef float v2f __attribute__((ext_vector_type(2)));

__device__ __forceinline__ float sigm(float x) { return 1.0f / (1.0f + expf(-x)); }

// packed fp32 fma (v_pk_fma_f32 on CDNA); fma semantics match the compiler's
// default contraction of a*b+c, so numerics are identical to the scalar code.
__device__ __forceinline__ v2f fma2(v2f a, v2f b, v2f c) {
#if __has_builtin(__builtin_elementwise_fma)
  return __builtin_elementwise_fma(a, b, c);
#else
  v2f r; r.x = __builtin_fmaf(a.x, b.x, c.x); r.y = __builtin_fmaf(a.y, b.y, c.y);
  return r;
#endif
}

__device__ __forceinline__ float wred(float x) {
#pragma unroll
  for (int off = 32; off > 0; off >>= 1) x += __shfl_xor(x, off, 64);
  return x;
}

// ---- device-coherent (bypass L1+L2) memory ops: always correct cross-XCD ----
__device__ __forceinline__ void load2_f4_sc(const float* p0, const float* p1,
                                            v4f& a, v4f& b) {
  asm volatile("global_load_dwordx4 %0, %2, off sc0 sc1\n\t"
               "global_load_dwordx4 %1, %3, off sc0 sc1\n\t"
               "s_waitcnt vmcnt(0)"
               : "=&v"(a), "=&v"(b) : "v"(p0), "v"(p1) : "memory");
}
__device__ __forceinline__ int load_i_sc(const int* p) {
  int r;
  asm volatile("global_load_dword %0, %1, off sc0 sc1\n\ts_waitcnt vmcnt(0)"
               : "=v"(r) : "v"(p) : "memory");
  return r;
}
__device__ __forceinline__ void store_f_sc(float* p, float v) {
  asm volatile("global_store_dword %0, %1, off sc0 sc1" :: "v"(p), "v"(v) : "memory");
}
__device__ __forceinline__ void store_i_sc(int* p, int v) {
  asm volatile("global_store_dword %0, %1, off sc0 sc1" :: "v"(p), "v"(v) : "memory");
}

// ---- VALU-pipe 32-lane reduction: 4x row_ror (row sums) + row_bcast15 ----
template <int CTRL, int RMASK>
__device__ __forceinline__ float dpp_add(float x) {
  int y = __builtin_amdgcn_update_dpp(0, __float_as_int(x), CTRL, RMASK, 0xF, false);
  return x + __int_as_float(y);
}
__device__ __forceinline__ float reduce32(float x) {
  x = dpp_add<0x121, 0xF>(x);  // row_ror:1
  x = dpp_add<0x122, 0xF>(x);  // row_ror:2
  x = dpp_add<0x124, 0xF>(x);  // row_ror:4
  x = dpp_add<0x128, 0xF>(x);  // row_ror:8  -> every lane holds its 16-row sum
  x = dpp_add<0x142, 0xA>(x);  // row_bcast15 into rows 1,3 -> kq>=16 = 32-sum
  return x;
}

// ---------------------------------------------------------------- init zeros
// flags are PADDED: one 64B line per flag -> flags[(grp*64+jb)*16]
__global__ void k_init(float* __restrict__ hbuf, int* __restrict__ flags) {
  int i = blockIdx.x * blockDim.x + threadIdx.x;
  if (i < 2 * 2 * BATCH * HID) hbuf[i] = 0.0f;   // [par][dir][b][HID]
  if (i < 4096) flags[i] = 0;                    // 256 flags x 16-int pad
}

// ------------------------------------------- L1 input projection, TWO chunks
// ROUND-11: pairwise MEGA-LAUNCH. Occupancy math: ~110 VGPR + 18.4KB LDS ->
// up to 4 blocks/CU = 1024 slots, but each per-chunk launch had only 384
// blocks -> machine ~62% idle while each block walks its latency chain
// (48 tiles x {2 barriers + LDS ping-pong}). Merging chunks 2p,2p+1 into one
// 768-block launch (blockIdx.z: bit0=dir, bit1=chunk-of-pair) lets blocks
// mutually hide those stalls. Kernel body identical -> bitwise numerics.
// Memory: 4 chunk buffers = round-1's proven 76MB footprint.
// (Round-8 reg prefetch; round-9 CMAP padding; round-7 lambda dbuf spilled.)
#define CMAP(c) ((c) + (((c) >> 5) << 2))
__global__ __launch_bounds__(256) void k_proj1(
    const float* __restrict__ emb,
    const float* __restrict__ w_f, const float* __restrict__ b_f,
    const float* __restrict__ w_r, const float* __restrict__ b_r,
    float* __restrict__ xs_f0, float* __restrict__ xs_r0,
    float* __restrict__ xs_f1, float* __restrict__ xs_r1, int chunk0) {
  __shared__ float As[16][144];
  __shared__ float Bs[16][144];
  const int tid = threadIdx.x;
  const int bn0 = blockIdx.x * 128;
  const int bb  = blockIdx.y;
  const int dir  = blockIdx.z & 1;
  const int cidx = blockIdx.z >> 1;
  const int chunk = chunk0 + cidx;
  const float* W    = dir ? w_r : w_f;
  const float* bias = dir ? b_r : b_f;
  float* xs = cidx ? (dir ? xs_r1 : xs_f1) : (dir ? xs_r0 : xs_f0);

  v2f acc2[8][4];
#pragma unroll
  for (int i = 0; i < 8; i++)
#pragma unroll
    for (int j = 0; j < 4; j++) acc2[i][j] = (v2f){0.0f, 0.0f};

  const int mload = tid & 127;
  const int kq0   = tid >> 7;
  const int tglob = dir ? (SEQ - 1 - (chunk * CHUNK + mload)) : (chunk * CHUNK + mload);
  const float* arow = emb + (size_t)(bb * SEQ + tglob) * HID;
  const float* brow = W + (size_t)(bn0 + mload) * HID;
  const int tm = tid & 15, tn = tid >> 4;
  const int cw = CMAP(mload);            // swizzled write column
  const int cA = CMAP(tm * 8);           // swizzled read col base (A)
  const int cB = CMAP(tn * 8);           // swizzled read col base (B)

  // per-thread load cursors: rep0 at +0, rep1 at +8 floats (kq = kq0, kq0+2)
  const float* aptr = arow + kq0 * 4;
  const float* bptr = brow + kq0 * 4;
  const int rA = kq0 * 4;          // LDS row base, rep0
  const int rB = (kq0 + 2) * 4;    // LDS row base, rep1

  // prologue: tile 0 -> regs
  float4 a0 = *(const float4*)(aptr);
  float4 a1 = *(const float4*)(aptr + 8);
  float4 b0 = *(const float4*)(bptr);
  float4 b1 = *(const float4*)(bptr + 8);

  for (int kt = 0; kt < HID; kt += 16) {
    // stage current tile regs -> LDS
    As[rA + 0][cw] = a0.x; As[rA + 1][cw] = a0.y;
    As[rA + 2][cw] = a0.z; As[rA + 3][cw] = a0.w;
    As[rB + 0][cw] = a1.x; As[rB + 1][cw] = a1.y;
    As[rB + 2][cw] = a1.z; As[rB + 3][cw] = a1.w;
    Bs[rA + 0][cw] = b0.x; Bs[rA + 1][cw] = b0.y;
    Bs[rA + 2][cw] = b0.z; Bs[rA + 3][cw] = b0.w;
    Bs[rB + 0][cw] = b1.x; Bs[rB + 1][cw] = b1.y;
    Bs[rB + 2][cw] = b1.z; Bs[rB + 3][cw] = b1.w;
    __syncthreads();
    // prefetch next tile (latency spans the compute below)
    if (kt + 16 < HID) {
      a0 = *(const float4*)(aptr + kt + 16);
      a1 = *(const float4*)(aptr + kt + 24);
      b0 = *(const float4*)(bptr + kt + 16);
      b1 = *(const float4*)(bptr + kt + 24);
    }
#pragma unroll
    for (int k = 0; k < 16; k++) {
      float4 c0 = *(const float4*)&As[k][cA];
      float4 c1 = *(const float4*)&As[k][cA + 4];
      float4 d0 = *(const float4*)&Bs[k][cB];
      float4 d1 = *(const float4*)&Bs[k][cB + 4];
      float av[8] = {c0.x, c0.y, c0.z, c0.w, c1.x, c1.y, c1.z, c1.w};
      v2f bv2[4] = {{d0.x, d0.y}, {d0.z, d0.w}, {d1.x, d1.y}, {d1.z, d1.w}};
#pragma unroll
      for (int i = 0; i < 8; i++) {
        v2f avv = {av[i], av[i]};
#pragma unroll
        for (int jj = 0; jj < 4; jj++) acc2[i][jj] = fma2(avv, bv2[jj], acc2[i][jj]);
      }
    }
    __syncthreads();
  }
#pragma unroll
  for (int i = 0; i < 8; i++) {
    int row = tm * 8 + i;
    size_t base = (size_t)(bb * CHUNK + row) * G4 + bn0 + tn * 8;
#pragma unroll
    for (int jj = 0; jj < 4; jj++) {
      xs[base + 2 * jj]     = acc2[i][jj].x + bias[bn0 + tn * 8 + 2 * jj];
      xs[base + 2 * jj + 1] = acc2[i][jj].y + bias[bn0 + tn * 8 + 2 * jj + 1];
    }
  }
}

// ---------------------------------------- L1 recurrence: persistent kernel
// VERIFIED OPTIMUM — 637-648us. 256 blocks x 384 threads. CLOSED after r9:
// all geometry perturbations regress (fused 888; packet 975; 128x768 1025 —
// FETCH dropped 25% yet time +58%, traffic is NOT the bottleneck). The
// ~5us/step = ~1.2us compute + ~3.8us cross-XCD publication chain is the
// protocol floor at this shape.
// ROUND-4: scalar dot chains (chain depth rules a serial chain).
// ROUND-8: harr history stores deferred past flag publication (free).
__global__ __launch_bounds__(384, 2) void k_rec1(
    const float* __restrict__ whh_f, const float* __restrict__ whh_r,
    const float* __restrict__ xs_f, const float* __restrict__ xs_r,
    float* __restrict__ hbuf, float* __restrict__ cbuf, int* __restrict__ flags,
    float* __restrict__ hf, float* __restrict__ hr, int t0, int init) {
  __shared__ float hlds[4 * HID];
  const int tid = threadIdx.x;
  const int bid = blockIdx.x;
  const int dir = bid >> 7;
  const int bh  = (bid >> 6) & 1;
  const int jb  = bid & 63;
  const int J0  = jb * 12;
  const int grp = dir * 2 + bh;
  const int g  = tid >> 5;
  const int kq = tid & 31;
  const int j  = J0 + g;

  const float* W  = dir ? whh_r : whh_f;
  const float* xs = dir ? xs_r  : xs_f;
  float* harr = dir ? hr : hf;

  // W_hh slice -> registers (once per chunk launch), interleaved k layout
  float wreg[4][24];
#pragma unroll
  for (int gate = 0; gate < 4; gate++) {
#pragma unroll
    for (int q = 0; q < 6; q++) {
      *(v4f*)&wreg[gate][q * 4] =
          *(const v4f*)&W[(size_t)(gate * HID + j) * HID + q * 128 + kq * 4];
    }
  }

  float cc[4];
#pragma unroll
  for (int b = 0; b < 4; b++) cc[b] = 0.0f;
  if (!init && kq == 16) {
#pragma unroll
    for (int b = 0; b < 4; b++) cc[b] = cbuf[bid * 48 + g * 4 + b];
  }

  for (int stp = 0; stp < CHUNK; stp++) {
    const int s = t0 + stp;
    const int par = s & 1;

    // prefetch xs gate values for writers BEFORE the wait (cached loads;
    // cannot sink past the asm memory clobbers in the poll loop)
    float xsv[4][4];
    if (kq == 16) {
#pragma unroll
      for (int b = 0; b < 4; b++) {
        const size_t xbase = (size_t)((bh * 4 + b) * CHUNK + stp) * G4 + j;
#pragma unroll
        for (int gate = 0; gate < 4; gate++)
          xsv[b][gate] = xs[xbase + gate * HID];
      }
    }

    // wait until all 64 blocks of this group published h_{s-1}
    if (tid < 64) {
      const int* fp = flags + (grp * 64 + tid) * 16;   // one line per flag
      while (load_i_sc(fp) < s) { __builtin_amdgcn_s_sleep(4); }
    }
    __syncthreads();

    // stage h_{s-1} (my dir, my 4 b's) into LDS
    {
      const float* src = hbuf + (size_t)((par * 2 + dir) * BATCH + bh * 4) * HID + tid * 8;
      v4f a, b4;
      load2_f4_sc(src, src + 4, a, b4);
      *(v4f*)&hlds[tid * 8]     = a;
      *(v4f*)&hlds[tid * 8 + 4] = b4;
    }
    __syncthreads();

    // dots: 4 gates x 4 b over this thread's interleaved k-slice
    float acc[4][4];
#pragma unroll
    for (int gate = 0; gate < 4; gate++)
#pragma unroll
      for (int b = 0; b < 4; b++) acc[gate][b] = 0.0f;
#pragma unroll
    for (int b = 0; b < 4; b++) {
      float hk[24];
#pragma unroll
      for (int q = 0; q < 6; q++)
        *(v4f*)&hk[q * 4] = *(const v4f*)&hlds[b * HID + q * 128 + kq * 4];
#pragma unroll
      for (int gate = 0; gate < 4; gate++)
#pragma unroll
        for (int k = 0; k < 24; k++) acc[gate][b] += wreg[gate][k] * hk[k];
    }
#pragma unroll
    for (int gate = 0; gate < 4; gate++)
#pragma unroll
      for (int b = 0; b < 4; b++) acc[gate][b] = reduce32(acc[gate][b]);

    // writers: LSTM pointwise + publish h (sc stores only on publish path)
    float hv[4];
    int t = 0;
    if (kq == 16) {
      t = dir ? (SEQ - 1 - s) : s;
#pragma unroll
      for (int b = 0; b < 4; b++) {
        const int bg = bh * 4 + b;
        float iv = acc[0][b] + xsv[b][0];
        float fv = acc[1][b] + xsv[b][1];
        float gv = acc[2][b] + xsv[b][2];
        float ov = acc[3][b] + xsv[b][3];
        cc[b] = sigm(fv) * cc[b] + sigm(iv) * tanhf(gv);
        hv[b] = sigm(ov) * tanhf(cc[b]);
        store_f_sc(hbuf + (size_t)(((par ^ 1) * 2 + dir) * BATCH + bg) * HID + j, hv[b]);
      }
    }
    asm volatile("s_waitcnt vmcnt(0)" ::: "memory");
    __syncthreads();
    if (tid == 0) store_i_sc(flags + (grp * 64 + jb) * 16, s + 1);
    // deferred history stores: off the publication critical path
    if (kq == 16) {
#pragma unroll
      for (int b = 0; b < 4; b++)
        harr[(size_t)((bh * 4 + b) * SEQ + t) * HID + j] = hv[b];
    }
  }
  if (kq == 16) {
#pragma unroll
    for (int b = 0; b < 4; b++) cbuf[bid * 48 + g * 4 + b] = cc[b];
  }
}

// ----------------------------------------------------------- hs = hf + hr
__global__ void k_sum(float* __restrict__ hf, const float* __restrict__ hr) {
  int i = blockIdx.x * 256 + threadIdx.x;
  float4 a = ((const float4*)hf)[i];
  float4 b = ((const float4*)hr)[i];
  a.x += b.x; a.y += b.y; a.z += b.z; a.w += b.w;
  ((float4*)hf)[i] = a;
}

// --------------------------------------------------------- windowed attention
__global__ __launch_bounds__(64) void k_attn(
    const float* __restrict__ hs, const float* __restrict__ attn_w,
    const float* __restrict__ attn_b, float* __restrict__ att) {
  const int l = threadIdx.x;
  const int s = blockIdx.x, b = blockIdx.y;
  const float* hrow = hs + (size_t)(b * SEQ + s) * HID;
  float v[12];
  float u1p = 0.0f;
#pragma unroll
  for (int jj = 0; jj < 12; jj++) {
    int d = l + 64 * jj;
    float x = hrow[d];
    u1p += x * attn_w[d];
    v[jj] = attn_w[HID + d] + x * attn_w[2 * HID + d];
  }
  float u1 = wred(u1p) + attn_b[0];
  float sc[21];
  for (int o = 0; o < 21; o++) {
    int s2 = s + o - 10;
    if (s2 >= 0 && s2 < SEQ) {
      const float* h2 = hs + (size_t)(b * SEQ + s2) * HID;
      float p = 0.0f;
#pragma unroll
      for (int jj = 0; jj < 12; jj++) p += h2[l + 64 * jj] * v[jj];
      sc[o] = wred(p) + u1;
    } else {
      sc[o] = NEGV;
    }
  }
  float m = sc[0];
#pragma unroll
  for (int o = 1; o < 21; o++) m = fmaxf(m, sc[o]);
  float sum = 0.0f;
#pragma unroll
  for (int o = 0; o < 21; o++) { sc[o] = expf(sc[o] - m); sum += sc[o]; }
  float inv = 1.0f / sum;
  float acc[12];
#pragma unroll
  for (int jj = 0; jj < 12; jj++) acc[jj] = 0.0f;
  for (int o = 0; o < 21; o++) {
    int s2 = s + o - 10;
    if (s2 < 0 || s2 >= SEQ) continue;
    float a = sc[o] * inv;
    const float* h2 = hs + (size_t)(b * SEQ + s2) * HID;
#pragma unroll
    for (int jj = 0; jj < 12; jj++) acc[jj] += a * h2[l + 64 * jj];
  }
  float* orow = att + (size_t)(b * SEQ + s) * HID;
#pragma unroll
  for (int jj = 0; jj < 12; jj++) orow[l + 64 * jj] = acc[jj];
}

// -------------------------------------------------------- L2 input projection
__global__ __launch_bounds__(256) void k_proj2(
    const float* __restrict__ hs, const float* __restrict__ att,
    const float* __restrict__ w2f, const float* __restrict__ b2f,
    const float* __restrict__ w2r, const float* __restrict__ b2r,
    float* __restrict__ xs2) {
  __shared__ __align__(16) float x2[2 * HID];
  __shared__ float part[32][9];
  const int tid = threadIdx.x;
  const int s = blockIdx.x, b = blockIdx.y;
  size_t base = (size_t)(b * SEQ + s) * HID;
  for (int i = tid; i < 2 * HID; i += 256)
    x2[i] = (i < HID) ? hs[base + i] : att[base + i - HID];
  __syncthreads();
  const int gid = tid & 31, pp = tid >> 5;
  const int d = gid >> 4, g = gid & 15;
  const float4* w4 = (const float4*)((d ? w2r : w2f) + (size_t)g * (2 * HID));
  const float4* x4 = (const float4*)x2;
  float p = 0.0f;
  for (int e = pp * 48; e < pp * 48 + 48; e++) {
    float4 xv = x4[e];
    float4 wv = w4[e];
    p += xv.x * wv.x + xv.y * wv.y + xv.z * wv.z + xv.w * wv.w;
  }
  part[gid][pp] = p;
  __syncthreads();
  if (tid < 32) {
    float sumv = (d ? b2r : b2f)[g];
#pragma unroll
    for (int q = 0; q < 8; q++) sumv += part[gid][q];
    xs2[(size_t)((d * BATCH + b) * SEQ + s) * 16 + g] = sumv;
  }
}

// ------------------------------------------------------------- L2 recurrence
// Wave-local: each (dir,batch) combo lives in 16 lanes of one wave;
// h exchanged by shfl (no __syncthreads, no LDS). xs2 load software-pipelined
// one step ahead so its L2 latency hides under the gate math.
__global__ __launch_bounds__(256) void k_rec2(
    const float* __restrict__ xs2,
    const float* __restrict__ whh_f, const float* __restrict__ whh_r,
    float* __restrict__ h2) {
  const int tid = threadIdx.x;
  const int lane = tid & 63;
  const int hb = (tid >> 6) * 4 + (lane >> 4);   // 0..15 = dir*8 + b
  const int g = lane & 15;
  const int d = hb >> 3;
  const int base = lane & 48;                     // first lane of my 16-lane group
  const float* whh = (d ? whh_r : whh_f) + g * 4;
  const float w0 = whh[0], w1 = whh[1], w2 = whh[2], w3 = whh[3];
  const float* xrow = xs2 + (size_t)hb * SEQ * 16 + g;
  float c = 0.0f, h = 0.0f;
  float xv = xrow[(d ? (SEQ - 1) : 0) * 16];
  for (int st = 0; st < SEQ; st++) {
    const int t = d ? (SEQ - 1 - st) : st;
    const int tn = d ? (SEQ - 2 - st) : (st + 1);
    float xnext = (st + 1 < SEQ) ? xrow[tn * 16] : 0.0f;
    float h0 = __shfl(h, base + 0, 64);
    float h1 = __shfl(h, base + 1, 64);
    float h2v = __shfl(h, base + 2, 64);
    float h3 = __shfl(h, base + 3, 64);
    float gv = xv + w0 * h0 + w1 * h1 + w2 * h2v + w3 * h3;
    const int jj = g & 3;
    float iv = __shfl(gv, base + jj, 64);
    float fv = __shfl(gv, base + 4 + jj, 64);
    float gq = __shfl(gv, base + 8 + jj, 64);
    float ov = __shfl(gv, base + 12 + jj, 64);
    c = sigm(fv) * c + sigm(iv) * tanhf(gq);
    h = sigm(ov) * tanhf(c);
    if (g < 4) h2[((size_t)hb * SEQ + t) * 4 + g] = h;
    xv = xnext;
  }
}

// ------------------------------------------------------------------ em = f+r
__global__ void k_em(const float* __restrict__ h2, float* __restrict__ out) {
  int i = blockIdx.x * 256 + threadIdx.x;
  if (i < BATCH * SEQ * 4) out[BATCH * SEQ + i] = h2[i] + h2[BATCH * SEQ * 4 + i];
}

// ------------------------------------------------------------------- viterbi
__global__ __launch_bounds__(32) void k_viterbi(
    float* __restrict__ out, const float* __restrict__ start,
    const float* __restrict__ endw, const float* __restrict__ trans) {
  __shared__ unsigned char bp[SEQ - 1][32];
  const int l = threadIdx.x;
  const int b = l >> 2, j = l & 3;
  const float* em = out + BATCH * SEQ;
  const float tr0 = trans[0 * 4 + j], tr1 = trans[1 * 4 + j];
  const float tr2 = trans[2 * 4 + j], tr3 = trans[3 * 4 + j];
  float score = start[j] + em[((size_t)b * SEQ + 0) * 4 + j];
  for (int t = 1; t < SEQ; t++) {
    float s0 = __shfl(score, b * 4 + 0, 64);
    float s1 = __shfl(score, b * 4 + 1, 64);
    float s2 = __shfl(score, b * 4 + 2, 64);
    float s3 = __shfl(score, b * 4 + 3, 64);
    float v0 = s0 + tr0, v1 = s1 + tr1, v2 = s2 + tr2, v3 = s3 + tr3;
    float best = v0; int arg = 0;
    if (v1 > best) { best = v1; arg = 1; }
    if (v2 > best) { best = v2; arg = 2; }
    if (v3 > best) { best = v3; arg = 3; }
    bp[t - 1][l] = (unsigned char)arg;
    score = best + em[((size_t)b * SEQ + t) * 4 + j];
  }
  score += endw[j];
  float f0 = __shfl(score, b * 4 + 0, 64);
  float f1 = __shfl(score, b * 4 + 1, 64);
  float f2 = __shfl(score, b * 4 + 2, 64);
  float f3 = __shfl(score, b * 4 + 3, 64);
  if (j == 0) {
    float bbv = f0; int last = 0;
    if (f1 > bbv) { bbv = f1; last = 1; }
    if (f2 > bbv) { bbv = f2; last = 2; }
    if (f3 > bbv) { bbv = f3; last = 3; }
    int tag = last;
    out[b * SEQ + (SEQ - 1)] = (float)tag;
    for (int t = SEQ - 2; t >= 0; t--) {
      tag = bp[t][b * 4 + tag];
      out[b * SEQ + t] = (float)tag;
    }
  }
}

// ------------------------------------------------------------------ launcher
extern "C" void kernel_launch(void* const* d_in, const int* in_sizes, int n_in,
                              void* d_out, int out_size, void* d_ws, size_t ws_size,
                              hipStream_t stream) {
  const float* emb      = (const float*)d_in[0];
  const float* l1f_wih  = (const float*)d_in[1];
  const float* l1f_whh  = (const float*)d_in[2];
  const float* l1f_b    = (const float*)d_in[3];
  const float* l1r_wih  = (const float*)d_in[4];
  const float* l1r_whh  = (const float*)d_in[5];
  const float* l1r_b    = (const float*)d_in[6];
  const float* attn_w   = (const float*)d_in[7];
  const float* attn_b   = (const float*)d_in[8];
  const float* l2f_wih  = (const float*)d_in[9];
  const float* l2f_whh  = (const float*)d_in[10];
  const float* l2f_b    = (const float*)d_in[11];
  const float* l2r_wih  = (const float*)d_in[12];
  const float* l2r_whh  = (const float*)d_in[13];
  const float* l2r_b    = (const float*)d_in[14];
  const float* crf_start= (const float*)d_in[15];
  const float* crf_end  = (const float*)d_in[16];
  const float* crf_trans= (const float*)d_in[17];

  float* ws = (float*)d_ws;
  const size_t NCH = (size_t)BATCH * CHUNK * G4;     // 3,145,728 floats
  // pairwise mega-proj: chunk-pair buffers {A: even chunk, B: odd chunk}
  // 4 x NCH = round-1's proven workspace footprint.
  float* xs_fA = ws;
  float* xs_rA = xs_fA + NCH;
  float* xs_fB = xs_rA + NCH;
  float* xs_rB = xs_fB + NCH;
  float* hf   = xs_rB + NCH;                         // [b][t][HID]
  float* hr   = hf + (size_t)BATCH * SEQ * HID;
  float* hbuf = hr + (size_t)BATCH * SEQ * HID;      // 24,576 floats
  float* cbuf = hbuf + 2 * 2 * BATCH * HID;          // 12,288 floats
  float* h2   = cbuf + 256 * 48;                     // 32,768 floats
  int*   flags= (int*)(h2 + 2 * BATCH * SEQ * 4);    // 4,096 ints (padded)
  float* xs2  = xs_fA;                               // overlay (post-L1)
  float* att  = xs_rA;                               // overlay (post-L1)
  float* hs   = hf;                                  // after k_sum, hf = hf+hr

  k_init<<<dim3(96), dim3(256), 0, stream>>>(hbuf, flags);

  for (int pair = 0; pair < 2; pair++) {
    // mega-proj: chunks 2*pair and 2*pair+1 in one 768-block launch
    k_proj1<<<dim3(24, 8, 4), dim3(256), 0, stream>>>(
        emb, l1f_wih, l1f_b, l1r_wih, l1r_b,
        xs_fA, xs_rA, xs_fB, xs_rB, 2 * pair);
    k_rec1<<<dim3(256), dim3(384), 0, stream>>>(
        l1f_whh, l1r_whh, xs_fA, xs_rA, hbuf, cbuf, flags, hf, hr,
        (2 * pair) * CHUNK, pair == 0 ? 1 : 0);
    k_rec1<<<dim3(256), dim3(384), 0, stream>>>(
        l1f_whh, l1r_whh, xs_fB, xs_rB, hbuf, cbuf, flags, hf, hr,
        (2 * pair + 1) * CHUNK, 0);
  }

  k_sum<<<dim3(3072), dim3(256), 0, stream>>>(hf, hr);
  k_attn<<<dim3(SEQ, BATCH), dim3(64), 0, stream>>>(hs, attn_w, attn_b, att);
  k_proj2<<<dim3(SEQ, BATCH), dim3(256), 0, stream>>>(
      hs, att, l2f_wih, l2f_b, l2r_wih, l2r_b, xs2);
  k_rec2<<<dim3(1), dim3(256), 0, stream>>>(xs2, l2f_whh, l2r_whh, h2);
  k_em<<<dim3(64), dim3(256), 0, stream>>>(h2, (float*)d_out);
  k_viterbi<<<dim3(1), dim3(32), 0, stream>>>((float*)d_out, crf_start, crf_end, crf_trans);
}

// Round 13
// 3517.341 us; speedup vs baseline: 1.4112x; 1.0205x over previous
//
#include <hip/hip_runtime.h>
#include <math.h>

#define SEQ 512
#define BATCH 8
#define HID 768
#define G4 3072           // 4*HID
#define CHUNK 128
#define NEGV (-1000000000.0f)

typedef float v4f __attribute__((ext_vector_type(4)));
typedef float v2f __attribute__((ext_vector_type(2)));

__device__ __forceinline__ float sigm(float x) { return 1.0f / (1.0f + expf(-x)); }

// packed fp32 fma (v_pk_fma_f32 on CDNA); fma semantics match the compiler's
// default contraction of a*b+c, so numerics are identical to the scalar code.
__device__ __forceinline__ v2f fma2(v2f a, v2f b, v2f c) {
#if __has_builtin(__builtin_elementwise_fma)
  return __builtin_elementwise_fma(a, b, c);
#else
  v2f r; r.x = __builtin_fmaf(a.x, b.x, c.x); r.y = __builtin_fmaf(a.y, b.y, c.y);
  return r;
#endif
}

__device__ __forceinline__ float wred(float x) {
#pragma unroll
  for (int off = 32; off > 0; off >>= 1) x += __shfl_xor(x, off, 64);
  return x;
}

// ---- device-coherent (bypass L1+L2) memory ops: always correct cross-XCD ----
__device__ __forceinline__ void load2_f4_sc(const float* p0, const float* p1,
                                            v4f& a, v4f& b) {
  asm volatile("global_load_dwordx4 %0, %2, off sc0 sc1\n\t"
               "global_load_dwordx4 %1, %3, off sc0 sc1\n\t"
               "s_waitcnt vmcnt(0)"
               : "=&v"(a), "=&v"(b) : "v"(p0), "v"(p1) : "memory");
}
__device__ __forceinline__ int load_i_sc(const int* p) {
  int r;
  asm volatile("global_load_dword %0, %1, off sc0 sc1\n\ts_waitcnt vmcnt(0)"
               : "=v"(r) : "v"(p) : "memory");
  return r;
}
__device__ __forceinline__ void store_f_sc(float* p, float v) {
  asm volatile("global_store_dword %0, %1, off sc0 sc1" :: "v"(p), "v"(v) : "memory");
}
__device__ __forceinline__ void store_i_sc(int* p, int v) {
  asm volatile("global_store_dword %0, %1, off sc0 sc1" :: "v"(p), "v"(v) : "memory");
}

// ---- VALU-pipe 32-lane reduction: 4x row_ror (row sums) + row_bcast15 ----
template <int CTRL, int RMASK>
__device__ __forceinline__ float dpp_add(float x) {
  int y = __builtin_amdgcn_update_dpp(0, __float_as_int(x), CTRL, RMASK, 0xF, false);
  return x + __int_as_float(y);
}
__device__ __forceinline__ float reduce32(float x) {
  x = dpp_add<0x121, 0xF>(x);  // row_ror:1
  x = dpp_add<0x122, 0xF>(x);  // row_ror:2
  x = dpp_add<0x124, 0xF>(x);  // row_ror:4
  x = dpp_add<0x128, 0xF>(x);  // row_ror:8  -> every lane holds its 16-row sum
  x = dpp_add<0x142, 0xA>(x);  // row_bcast15 into rows 1,3 -> kq>=16 = 32-sum
  return x;
}

// ---------------------------------------------------------------- init zeros
// flags are PADDED: one 64B line per flag -> flags[(grp*64+jb)*16]
__global__ void k_init(float* __restrict__ hbuf, int* __restrict__ flags) {
  int i = blockIdx.x * blockDim.x + threadIdx.x;
  if (i < 2 * 2 * BATCH * HID) hbuf[i] = 0.0f;   // [par][dir][b][HID]
  if (i < 4096) flags[i] = 0;                    // 256 flags x 16-int pad
}

// ------------------------------------------- L1 input projection, TWO chunks
// ROUND-13 (= round-12 proj, resubmitted after container failure; the risky
// 80KB-LDS fused tail is reverted — it was the likely container killer).
// Straight-line DOUBLE-BUFFERED LDS: one barrier per k-tile (48 vs 96);
// tile t+1's stage-writes overlap tile t's compute (different buffer, race-
// free across the barrier). ONE float4x4 prefetch set + macro-literal buf
// indices (round-7's lambda version spilled to 256 VGPR). Same loads, same
// k-order pk_fma chains -> bitwise-identical numerics.
// (r9 CMAP padding; r11 pairwise mega-launch: blockIdx.z bit0=dir bit1=chunk.)
#define CMAP(c) ((c) + (((c) >> 5) << 2))
#define PROJ_WRITE(BUF)                                          \
  do {                                                           \
    As[BUF][rA + 0][cw] = a0.x; As[BUF][rA + 1][cw] = a0.y;      \
    As[BUF][rA + 2][cw] = a0.z; As[BUF][rA + 3][cw] = a0.w;      \
    As[BUF][rB + 0][cw] = a1.x; As[BUF][rB + 1][cw] = a1.y;      \
    As[BUF][rB + 2][cw] = a1.z; As[BUF][rB + 3][cw] = a1.w;      \
    Bs[BUF][rA + 0][cw] = b0.x; Bs[BUF][rA + 1][cw] = b0.y;      \
    Bs[BUF][rA + 2][cw] = b0.z; Bs[BUF][rA + 3][cw] = b0.w;      \
    Bs[BUF][rB + 0][cw] = b1.x; Bs[BUF][rB + 1][cw] = b1.y;      \
    Bs[BUF][rB + 2][cw] = b1.z; Bs[BUF][rB + 3][cw] = b1.w;      \
  } while (0)
#define PROJ_COMP(BUF)                                                        \
  do {                                                                        \
    _Pragma("unroll") for (int k = 0; k < 16; k++) {                          \
      float4 c0 = *(const float4*)&As[BUF][k][cA];                            \
      float4 c1 = *(const float4*)&As[BUF][k][cA + 4];                        \
      float4 d0 = *(const float4*)&Bs[BUF][k][cB];                            \
      float4 d1 = *(const float4*)&Bs[BUF][k][cB + 4];                        \
      float av[8] = {c0.x, c0.y, c0.z, c0.w, c1.x, c1.y, c1.z, c1.w};         \
      v2f bv2[4] = {{d0.x, d0.y}, {d0.z, d0.w}, {d1.x, d1.y}, {d1.z, d1.w}};  \
      _Pragma("unroll") for (int i = 0; i < 8; i++) {                         \
        v2f avv = {av[i], av[i]};                                             \
        _Pragma("unroll") for (int jj = 0; jj < 4; jj++)                      \
          acc2[i][jj] = fma2(avv, bv2[jj], acc2[i][jj]);                      \
      }                                                                       \
    }                                                                         \
  } while (0)
#define PROJ_LOAD(OFF)                              \
  do {                                              \
    a0 = *(const float4*)(aptr + (OFF));            \
    a1 = *(const float4*)(aptr + (OFF) + 8);        \
    b0 = *(const float4*)(bptr + (OFF));            \
    b1 = *(const float4*)(bptr + (OFF) + 8);        \
  } while (0)
__global__ __launch_bounds__(256) void k_proj1(
    const float* __restrict__ emb,
    const float* __restrict__ w_f, const float* __restrict__ b_f,
    const float* __restrict__ w_r, const float* __restrict__ b_r,
    float* __restrict__ xs_f0, float* __restrict__ xs_r0,
    float* __restrict__ xs_f1, float* __restrict__ xs_r1, int chunk0) {
  __shared__ float As[2][16][144];
  __shared__ float Bs[2][16][144];
  const int tid = threadIdx.x;
  const int bn0 = blockIdx.x * 128;
  const int bb  = blockIdx.y;
  const int dir  = blockIdx.z & 1;
  const int cidx = blockIdx.z >> 1;
  const int chunk = chunk0 + cidx;
  const float* W    = dir ? w_r : w_f;
  const float* bias = dir ? b_r : b_f;
  float* xs = cidx ? (dir ? xs_r1 : xs_f1) : (dir ? xs_r0 : xs_f0);

  v2f acc2[8][4];
#pragma unroll
  for (int i = 0; i < 8; i++)
#pragma unroll
    for (int j = 0; j < 4; j++) acc2[i][j] = (v2f){0.0f, 0.0f};

  const int mload = tid & 127;
  const int kq0   = tid >> 7;
  const int tglob = dir ? (SEQ - 1 - (chunk * CHUNK + mload)) : (chunk * CHUNK + mload);
  const float* arow = emb + (size_t)(bb * SEQ + tglob) * HID;
  const float* brow = W + (size_t)(bn0 + mload) * HID;
  const int tm = tid & 15, tn = tid >> 4;
  const int cw = CMAP(mload);            // swizzled write column
  const int cA = CMAP(tm * 8);           // swizzled read col base (A)
  const int cB = CMAP(tn * 8);           // swizzled read col base (B)

  // per-thread load cursors: rep0 at +0, rep1 at +8 floats (kq = kq0, kq0+2)
  const float* aptr = arow + kq0 * 4;
  const float* bptr = brow + kq0 * 4;
  const int rA = kq0 * 4;          // LDS row base, rep0
  const int rB = (kq0 + 2) * 4;    // LDS row base, rep1

  float4 a0, a1, b0, b1;
  // prologue: tile0 -> buf0; tile1 -> regs
  PROJ_LOAD(0);
  PROJ_WRITE(0);
  PROJ_LOAD(16);
  __syncthreads();

  // main: tiles 0..45 (tile t lives in buf[t&1]); one barrier per tile
  for (int p = 0; p < 23; p++) {
    const int kt2 = p * 32;
    PROJ_WRITE(1);             // stage tile 2p+1 (regs) -> buf1
    PROJ_LOAD(kt2 + 32);       // prefetch tile 2p+2
    PROJ_COMP(0);              // compute tile 2p
    __syncthreads();
    PROJ_WRITE(0);             // stage tile 2p+2 -> buf0
    PROJ_LOAD(kt2 + 48);       // prefetch tile 2p+3
    PROJ_COMP(1);              // compute tile 2p+1
    __syncthreads();
  }
  // epilogue: tiles 46,47 (regs hold tile 47 from p=22 phase B)
  PROJ_WRITE(1);               // stage tile 47 -> buf1
  PROJ_COMP(0);                // compute tile 46
  __syncthreads();
  PROJ_COMP(1);                // compute tile 47

#pragma unroll
  for (int i = 0; i < 8; i++) {
    int row = tm * 8 + i;
    size_t base = (size_t)(bb * CHUNK + row) * G4 + bn0 + tn * 8;
#pragma unroll
    for (int jj = 0; jj < 4; jj++) {
      xs[base + 2 * jj]     = acc2[i][jj].x + bias[bn0 + tn * 8 + 2 * jj];
      xs[base + 2 * jj + 1] = acc2[i][jj].y + bias[bn0 + tn * 8 + 2 * jj + 1];
    }
  }
}

// ---------------------------------------- L1 recurrence: persistent kernel
// VERIFIED OPTIMUM — 637-660us band. 256 blocks x 384 threads. CLOSED (r9):
// all geometry perturbations regress (fused 888; packet 975; 128x768 1025 —
// FETCH dropped 25% yet time +58%: traffic is NOT the bottleneck). The
// ~5us/step = ~1.2us compute + ~3.8us cross-XCD publication chain is the
// protocol floor at this shape.
// ROUND-4: scalar dot chains (chain depth rules a serial chain).
// ROUND-8: harr history stores deferred past flag publication (free).
__global__ __launch_bounds__(384, 2) void k_rec1(
    const float* __restrict__ whh_f, const float* __restrict__ whh_r,
    const float* __restrict__ xs_f, const float* __restrict__ xs_r,
    float* __restrict__ hbuf, float* __restrict__ cbuf, int* __restrict__ flags,
    float* __restrict__ hf, float* __restrict__ hr, int t0, int init) {
  __shared__ float hlds[4 * HID];
  const int tid = threadIdx.x;
  const int bid = blockIdx.x;
  const int dir = bid >> 7;
  const int bh  = (bid >> 6) & 1;
  const int jb  = bid & 63;
  const int J0  = jb * 12;
  const int grp = dir * 2 + bh;
  const int g  = tid >> 5;
  const int kq = tid & 31;
  const int j  = J0 + g;

  const float* W  = dir ? whh_r : whh_f;
  const float* xs = dir ? xs_r  : xs_f;
  float* harr = dir ? hr : hf;

  // W_hh slice -> registers (once per chunk launch), interleaved k layout
  float wreg[4][24];
#pragma unroll
  for (int gate = 0; gate < 4; gate++) {
#pragma unroll
    for (int q = 0; q < 6; q++) {
      *(v4f*)&wreg[gate][q * 4] =
          *(const v4f*)&W[(size_t)(gate * HID + j) * HID + q * 128 + kq * 4];
    }
  }

  float cc[4];
#pragma unroll
  for (int b = 0; b < 4; b++) cc[b] = 0.0f;
  if (!init && kq == 16) {
#pragma unroll
    for (int b = 0; b < 4; b++) cc[b] = cbuf[bid * 48 + g * 4 + b];
  }

  for (int stp = 0; stp < CHUNK; stp++) {
    const int s = t0 + stp;
    const int par = s & 1;

    // prefetch xs gate values for writers BEFORE the wait (cached loads;
    // cannot sink past the asm memory clobbers in the poll loop)
    float xsv[4][4];
    if (kq == 16) {
#pragma unroll
      for (int b = 0; b < 4; b++) {
        const size_t xbase = (size_t)((bh * 4 + b) * CHUNK + stp) * G4 + j;
#pragma unroll
        for (int gate = 0; gate < 4; gate++)
          xsv[b][gate] = xs[xbase + gate * HID];
      }
    }

    // wait until all 64 blocks of this group published h_{s-1}
    if (tid < 64) {
      const int* fp = flags + (grp * 64 + tid) * 16;   // one line per flag
      while (load_i_sc(fp) < s) { __builtin_amdgcn_s_sleep(4); }
    }
    __syncthreads();

    // stage h_{s-1} (my dir, my 4 b's) into LDS
    {
      const float* src = hbuf + (size_t)((par * 2 + dir) * BATCH + bh * 4) * HID + tid * 8;
      v4f a, b4;
      load2_f4_sc(src, src + 4, a, b4);
      *(v4f*)&hlds[tid * 8]     = a;
      *(v4f*)&hlds[tid * 8 + 4] = b4;
    }
    __syncthreads();

    // dots: 4 gates x 4 b over this thread's interleaved k-slice
    float acc[4][4];
#pragma unroll
    for (int gate = 0; gate < 4; gate++)
#pragma unroll
      for (int b = 0; b < 4; b++) acc[gate][b] = 0.0f;
#pragma unroll
    for (int b = 0; b < 4; b++) {
      float hk[24];
#pragma unroll
      for (int q = 0; q < 6; q++)
        *(v4f*)&hk[q * 4] = *(const v4f*)&hlds[b * HID + q * 128 + kq * 4];
#pragma unroll
      for (int gate = 0; gate < 4; gate++)
#pragma unroll
        for (int k = 0; k < 24; k++) acc[gate][b] += wreg[gate][k] * hk[k];
    }
#pragma unroll
    for (int gate = 0; gate < 4; gate++)
#pragma unroll
      for (int b = 0; b < 4; b++) acc[gate][b] = reduce32(acc[gate][b]);

    // writers: LSTM pointwise + publish h (sc stores only on publish path)
    float hv[4];
    int t = 0;
    if (kq == 16) {
      t = dir ? (SEQ - 1 - s) : s;
#pragma unroll
      for (int b = 0; b < 4; b++) {
        const int bg = bh * 4 + b;
        float iv = acc[0][b] + xsv[b][0];
        float fv = acc[1][b] + xsv[b][1];
        float gv = acc[2][b] + xsv[b][2];
        float ov = acc[3][b] + xsv[b][3];
        cc[b] = sigm(fv) * cc[b] + sigm(iv) * tanhf(gv);
        hv[b] = sigm(ov) * tanhf(cc[b]);
        store_f_sc(hbuf + (size_t)(((par ^ 1) * 2 + dir) * BATCH + bg) * HID + j, hv[b]);
      }
    }
    asm volatile("s_waitcnt vmcnt(0)" ::: "memory");
    __syncthreads();
    if (tid == 0) store_i_sc(flags + (grp * 64 + jb) * 16, s + 1);
    // deferred history stores: off the publication critical path
    if (kq == 16) {
#pragma unroll
      for (int b = 0; b < 4; b++)
        harr[(size_t)((bh * 4 + b) * SEQ + t) * HID + j] = hv[b];
    }
  }
  if (kq == 16) {
#pragma unroll
    for (int b = 0; b < 4; b++) cbuf[bid * 48 + g * 4 + b] = cc[b];
  }
}

// ----------------------------------------------------------- hs = hf + hr
__global__ void k_sum(float* __restrict__ hf, const float* __restrict__ hr) {
  int i = blockIdx.x * 256 + threadIdx.x;
  float4 a = ((const float4*)hf)[i];
  float4 b = ((const float4*)hr)[i];
  a.x += b.x; a.y += b.y; a.z += b.z; a.w += b.w;
  ((float4*)hf)[i] = a;
}

// --------------------------------------------------------- windowed attention
__global__ __launch_bounds__(64) void k_attn(
    const float* __restrict__ hs, const float* __restrict__ attn_w,
    const float* __restrict__ attn_b, float* __restrict__ att) {
  const int l = threadIdx.x;
  const int s = blockIdx.x, b = blockIdx.y;
  const float* hrow = hs + (size_t)(b * SEQ + s) * HID;
  float v[12];
  float u1p = 0.0f;
#pragma unroll
  for (int jj = 0; jj < 12; jj++) {
    int d = l + 64 * jj;
    float x = hrow[d];
    u1p += x * attn_w[d];
    v[jj] = attn_w[HID + d] + x * attn_w[2 * HID + d];
  }
  float u1 = wred(u1p) + attn_b[0];
  float sc[21];
  for (int o = 0; o < 21; o++) {
    int s2 = s + o - 10;
    if (s2 >= 0 && s2 < SEQ) {
      const float* h2 = hs + (size_t)(b * SEQ + s2) * HID;
      float p = 0.0f;
#pragma unroll
      for (int jj = 0; jj < 12; jj++) p += h2[l + 64 * jj] * v[jj];
      sc[o] = wred(p) + u1;
    } else {
      sc[o] = NEGV;
    }
  }
  float m = sc[0];
#pragma unroll
  for (int o = 1; o < 21; o++) m = fmaxf(m, sc[o]);
  float sum = 0.0f;
#pragma unroll
  for (int o = 0; o < 21; o++) { sc[o] = expf(sc[o] - m); sum += sc[o]; }
  float inv = 1.0f / sum;
  float acc[12];
#pragma unroll
  for (int jj = 0; jj < 12; jj++) acc[jj] = 0.0f;
  for (int o = 0; o < 21; o++) {
    int s2 = s + o - 10;
    if (s2 < 0 || s2 >= SEQ) continue;
    float a = sc[o] * inv;
    const float* h2 = hs + (size_t)(b * SEQ + s2) * HID;
#pragma unroll
    for (int jj = 0; jj < 12; jj++) acc[jj] += a * h2[l + 64 * jj];
  }
  float* orow = att + (size_t)(b * SEQ + s) * HID;
#pragma unroll
  for (int jj = 0; jj < 12; jj++) orow[l + 64 * jj] = acc[jj];
}

// -------------------------------------------------------- L2 input projection
__global__ __launch_bounds__(256) void k_proj2(
    const float* __restrict__ hs, const float* __restrict__ att,
    const float* __restrict__ w2f, const float* __restrict__ b2f,
    const float* __restrict__ w2r, const float* __restrict__ b2r,
    float* __restrict__ xs2) {
  __shared__ __align__(16) float x2[2 * HID];
  __shared__ float part[32][9];
  const int tid = threadIdx.x;
  const int s = blockIdx.x, b = blockIdx.y;
  size_t base = (size_t)(b * SEQ + s) * HID;
  for (int i = tid; i < 2 * HID; i += 256)
    x2[i] = (i < HID) ? hs[base + i] : att[base + i - HID];
  __syncthreads();
  const int gid = tid & 31, pp = tid >> 5;
  const int d = gid >> 4, g = gid & 15;
  const float4* w4 = (const float4*)((d ? w2r : w2f) + (size_t)g * (2 * HID));
  const float4* x4 = (const float4*)x2;
  float p = 0.0f;
  for (int e = pp * 48; e < pp * 48 + 48; e++) {
    float4 xv = x4[e];
    float4 wv = w4[e];
    p += xv.x * wv.x + xv.y * wv.y + xv.z * wv.z + xv.w * wv.w;
  }
  part[gid][pp] = p;
  __syncthreads();
  if (tid < 32) {
    float sumv = (d ? b2r : b2f)[g];
#pragma unroll
    for (int q = 0; q < 8; q++) sumv += part[gid][q];
    xs2[(size_t)((d * BATCH + b) * SEQ + s) * 16 + g] = sumv;
  }
}

// ------------------------------------------------------------- L2 recurrence
// Wave-local: each (dir,batch) combo lives in 16 lanes of one wave;
// h exchanged by shfl (no __syncthreads, no LDS). xs2 load software-pipelined
// one step ahead so its L2 latency hides under the gate math.
__global__ __launch_bounds__(256) void k_rec2(
    const float* __restrict__ xs2,
    const float* __restrict__ whh_f, const float* __restrict__ whh_r,
    float* __restrict__ h2) {
  const int tid = threadIdx.x;
  const int lane = tid & 63;
  const int hb = (tid >> 6) * 4 + (lane >> 4);   // 0..15 = dir*8 + b
  const int g = lane & 15;
  const int d = hb >> 3;
  const int base = lane & 48;                     // first lane of my 16-lane group
  const float* whh = (d ? whh_r : whh_f) + g * 4;
  const float w0 = whh[0], w1 = whh[1], w2 = whh[2], w3 = whh[3];
  const float* xrow = xs2 + (size_t)hb * SEQ * 16 + g;
  float c = 0.0f, h = 0.0f;
  float xv = xrow[(d ? (SEQ - 1) : 0) * 16];
  for (int st = 0; st < SEQ; st++) {
    const int t = d ? (SEQ - 1 - st) : st;
    const int tn = d ? (SEQ - 2 - st) : (st + 1);
    float xnext = (st + 1 < SEQ) ? xrow[tn * 16] : 0.0f;
    float h0 = __shfl(h, base + 0, 64);
    float h1 = __shfl(h, base + 1, 64);
    float h2v = __shfl(h, base + 2, 64);
    float h3 = __shfl(h, base + 3, 64);
    float gv = xv + w0 * h0 + w1 * h1 + w2 * h2v + w3 * h3;
    const int jj = g & 3;
    float iv = __shfl(gv, base + jj, 64);
    float fv = __shfl(gv, base + 4 + jj, 64);
    float gq = __shfl(gv, base + 8 + jj, 64);
    float ov = __shfl(gv, base + 12 + jj, 64);
    c = sigm(fv) * c + sigm(iv) * tanhf(gq);
    h = sigm(ov) * tanhf(c);
    if (g < 4) h2[((size_t)hb * SEQ + t) * 4 + g] = h;
    xv = xnext;
  }
}

// ------------------------------------------------------------------ em = f+r
__global__ void k_em(const float* __restrict__ h2, float* __restrict__ out) {
  int i = blockIdx.x * 256 + threadIdx.x;
  if (i < BATCH * SEQ * 4) out[BATCH * SEQ + i] = h2[i] + h2[BATCH * SEQ * 4 + i];
}

// ------------------------------------------------------------------- viterbi
__global__ __launch_bounds__(32) void k_viterbi(
    float* __restrict__ out, const float* __restrict__ start,
    const float* __restrict__ endw, const float* __restrict__ trans) {
  __shared__ unsigned char bp[SEQ - 1][32];
  const int l = threadIdx.x;
  const int b = l >> 2, j = l & 3;
  const float* em = out + BATCH * SEQ;
  const float tr0 = trans[0 * 4 + j], tr1 = trans[1 * 4 + j];
  const float tr2 = trans[2 * 4 + j], tr3 = trans[3 * 4 + j];
  float score = start[j] + em[((size_t)b * SEQ + 0) * 4 + j];
  for (int t = 1; t < SEQ; t++) {
    float s0 = __shfl(score, b * 4 + 0, 64);
    float s1 = __shfl(score, b * 4 + 1, 64);
    float s2 = __shfl(score, b * 4 + 2, 64);
    float s3 = __shfl(score, b * 4 + 3, 64);
    float v0 = s0 + tr0, v1 = s1 + tr1, v2 = s2 + tr2, v3 = s3 + tr3;
    float best = v0; int arg = 0;
    if (v1 > best) { best = v1; arg = 1; }
    if (v2 > best) { best = v2; arg = 2; }
    if (v3 > best) { best = v3; arg = 3; }
    bp[t - 1][l] = (unsigned char)arg;
    score = best + em[((size_t)b * SEQ + t) * 4 + j];
  }
  score += endw[j];
  float f0 = __shfl(score, b * 4 + 0, 64);
  float f1 = __shfl(score, b * 4 + 1, 64);
  float f2 = __shfl(score, b * 4 + 2, 64);
  float f3 = __shfl(score, b * 4 + 3, 64);
  if (j == 0) {
    float bbv = f0; int last = 0;
    if (f1 > bbv) { bbv = f1; last = 1; }
    if (f2 > bbv) { bbv = f2; last = 2; }
    if (f3 > bbv) { bbv = f3; last = 3; }
    int tag = last;
    out[b * SEQ + (SEQ - 1)] = (float)tag;
    for (int t = SEQ - 2; t >= 0; t--) {
      tag = bp[t][b * 4 + tag];
      out[b * SEQ + t] = (float)tag;
    }
  }
}

// ------------------------------------------------------------------ launcher
extern "C" void kernel_launch(void* const* d_in, const int* in_sizes, int n_in,
                              void* d_out, int out_size, void* d_ws, size_t ws_size,
                              hipStream_t stream) {
  const float* emb      = (const float*)d_in[0];
  const float* l1f_wih  = (const float*)d_in[1];
  const float* l1f_whh  = (const float*)d_in[2];
  const float* l1f_b    = (const float*)d_in[3];
  const float* l1r_wih  = (const float*)d_in[4];
  const float* l1r_whh  = (const float*)d_in[5];
  const float* l1r_b    = (const float*)d_in[6];
  const float* attn_w   = (const float*)d_in[7];
  const float* attn_b   = (const float*)d_in[8];
  const float* l2f_wih  = (const float*)d_in[9];
  const float* l2f_whh  = (const float*)d_in[10];
  const float* l2f_b    = (const float*)d_in[11];
  const float* l2r_wih  = (const float*)d_in[12];
  const float* l2r_whh  = (const float*)d_in[13];
  const float* l2r_b    = (const float*)d_in[14];
  const float* crf_start= (const float*)d_in[15];
  const float* crf_end  = (const float*)d_in[16];
  const float* crf_trans= (const float*)d_in[17];

  float* ws = (float*)d_ws;
  const size_t NCH = (size_t)BATCH * CHUNK * G4;     // 3,145,728 floats
  // pairwise mega-proj: chunk-pair buffers {A: even chunk, B: odd chunk}
  float* xs_fA = ws;
  float* xs_rA = xs_fA + NCH;
  float* xs_fB = xs_rA + NCH;
  float* xs_rB = xs_fB + NCH;
  float* hf   = xs_rB + NCH;                         // [b][t][HID]
  float* hr   = hf + (size_t)BATCH * SEQ * HID;
  float* hbuf = hr + (size_t)BATCH * SEQ * HID;      // 24,576 floats
  float* cbuf = hbuf + 2 * 2 * BATCH * HID;          // 12,288 floats
  float* h2   = cbuf + 256 * 48;                     // 32,768 floats
  int*   flags= (int*)(h2 + 2 * BATCH * SEQ * 4);    // 4,096 ints (padded)
  float* xs2  = xs_fA;                               // overlay (post-L1)
  float* att  = xs_rA;                               // overlay (post-L1)
  float* hs   = hf;                                  // after k_sum, hf = hf+hr

  k_init<<<dim3(96), dim3(256), 0, stream>>>(hbuf, flags);

  for (int pair = 0; pair < 2; pair++) {
    // mega-proj: chunks 2*pair and 2*pair+1 in one 768-block launch
    k_proj1<<<dim3(24, 8, 4), dim3(256), 0, stream>>>(
        emb, l1f_wih, l1f_b, l1r_wih, l1r_b,
        xs_fA, xs_rA, xs_fB, xs_rB, 2 * pair);
    k_rec1<<<dim3(256), dim3(384), 0, stream>>>(
        l1f_whh, l1r_whh, xs_fA, xs_rA, hbuf, cbuf, flags, hf, hr,
        (2 * pair) * CHUNK, pair == 0 ? 1 : 0);
    k_rec1<<<dim3(256), dim3(384), 0, stream>>>(
        l1f_whh, l1r_whh, xs_fB, xs_rB, hbuf, cbuf, flags, hf, hr,
        (2 * pair + 1) * CHUNK, 0);
  }

  k_sum<<<dim3(3072), dim3(256), 0, stream>>>(hf, hr);
  k_attn<<<dim3(SEQ, BATCH), dim3(64), 0, stream>>>(hs, attn_w, attn_b, att);
  k_proj2<<<dim3(SEQ, BATCH), dim3(256), 0, stream>>>(
      hs, att, l2f_wih, l2f_b, l2r_wih, l2r_b, xs2);
  k_rec2<<<dim3(1), dim3(256), 0, stream>>>(xs2, l2f_whh, l2r_whh, h2);
  k_em<<<dim3(64), dim3(256), 0, stream>>>(h2, (float*)d_out);
  k_viterbi<<<dim3(1), dim3(32), 0, stream>>>((float*)d_out, crf_start, crf_end, crf_trans);
}